// Round 13
// baseline (656.304 us; speedup 1.0000x reference)
//
#include <hip/hip_runtime.h>
#include <hip/hip_bf16.h>
#include <math.h>

#define B_   64
#define NN_  1000
#define NV_  10
#define H_   128
#define FS_  8
#define FV_  6
#define T_   8
#define O_   64
#define EN_  512000
#define EV_  2560
#define NS_  (B_*NN_)   /* 64000 */
#define NVT_ (B_*NV_)   /* 640 */
#define RNG_S (NS_/8)   /* 8000 dst nodes per XCD range */
#define RNG_V (NVT_/8)  /* 80 */

typedef __attribute__((ext_vector_type(8))) short short8v;   // 8 bf16
typedef __attribute__((ext_vector_type(4))) float floatx4;

__device__ __forceinline__ float fast_rcp(float x) { return __builtin_amdgcn_rcpf(x); }
__device__ __forceinline__ float fast_tanh(float x) {
  return 1.f - 2.f*fast_rcp(1.f + __expf(2.f*x));
}
__device__ __forceinline__ float fast_sigmoid(float x) {
  return fast_rcp(1.f + __expf(-x));
}
__device__ __forceinline__ unsigned short bf16_rne(float x) {
  unsigned u = __float_as_uint(x);
  return (unsigned short)((u + 0x7FFFu + ((u >> 16) & 1u)) >> 16);
}
__device__ __forceinline__ float bf16_tof(unsigned short b) {
  return __uint_as_float(((unsigned)b) << 16);
}
__device__ __forceinline__ float dot4(float4 a, float4 b) {
  return a.x*b.x + a.y*b.y + a.z*b.z + a.w*b.w;
}
__device__ __forceinline__ float lrelu02(float e) {
  return (e > 0.f) ? e : 0.2f*e;
}

// ---------- CSR build: XCD-ranged count (atomics stay in one XCD's L2) ----------
__global__ __launch_bounds__(256) void k_count_r(const int* __restrict__ dst_s,
                                                 const int* __restrict__ dst_v,
                                                 int* __restrict__ counts_s,
                                                 int* __restrict__ counts_v) {
  int bid = blockIdx.x;
  int r = bid & 7;
  int i = (bid >> 3)*256 + threadIdx.x;
  if (i < EN_) {
    int d = dst_s[i];
    int lo = r*RNG_S;
    if (d >= lo && d < lo + RNG_S) atomicAdd(&counts_s[d], 1);
  } else if (i < EN_ + EV_) {
    int d = dst_v[i - EN_];
    int lo = r*RNG_V;
    if (d >= lo && d < lo + RNG_V) atomicAdd(&counts_v[d], 1);
  }
}

__global__ __launch_bounds__(256) void k_scan_local(const int* cnt, int n, int* out, int* bsum) {
  __shared__ int s[256];
  int t = threadIdx.x; int i = blockIdx.x*256 + t;
  int v = (i < n) ? cnt[i] : 0;
  s[t] = v; __syncthreads();
  #pragma unroll
  for (int o = 1; o < 256; o <<= 1) {
    int u = (t >= o) ? s[t-o] : 0; __syncthreads();
    s[t] += u; __syncthreads();
  }
  if (i < n) out[i] = s[t] - v;
  if (t == 255) bsum[blockIdx.x] = s[255];
}

__global__ __launch_bounds__(1024) void k_scan_small(int* bsum, int nb,
                                                     const int* cntv, int* rowptr_v, int nv) {
  __shared__ int sums[1024];
  int t = threadIdx.x;
  if (blockIdx.x == 0) {
    int v = (t < nb) ? bsum[t] : 0;
    sums[t] = v; __syncthreads();
    for (int o = 1; o < 1024; o <<= 1) {
      int u = (t >= o) ? sums[t-o] : 0; __syncthreads();
      sums[t] += u; __syncthreads();
    }
    if (t < nb) bsum[t] = sums[t] - v;
  } else {
    int v = (t < nv) ? cntv[t] : 0;
    sums[t] = v; __syncthreads();
    for (int o = 1; o < 1024; o <<= 1) {
      int u = (t >= o) ? sums[t-o] : 0; __syncthreads();
      sums[t] += u; __syncthreads();
    }
    if (t < nv) rowptr_v[t] = sums[t] - v;
    if (t == nv-1) rowptr_v[nv] = sums[t];
  }
}

__global__ __launch_bounds__(256) void k_scan_add(int* out, const int* bsum, int n, int E) {
  int i = blockIdx.x*256 + threadIdx.x;
  if (i < n) out[i] += bsum[blockIdx.x];
  if (i == 0) out[n] = E;
}

__global__ __launch_bounds__(256) void k_scatter_r(const int* __restrict__ src_s,
                                                   const int* __restrict__ dst_s,
                                                   const int* __restrict__ src_v,
                                                   const int* __restrict__ dst_v,
                                                   const int* __restrict__ rowptr_s,
                                                   const int* __restrict__ rowptr_v,
                                                   int* __restrict__ cursor_s,
                                                   int* __restrict__ cursor_v,
                                                   unsigned short* __restrict__ srcp_s,
                                                   unsigned short* __restrict__ srcp_v) {
  int bid = blockIdx.x;
  int r = bid & 7;
  int i = (bid >> 3)*256 + threadIdx.x;
  if (i < EN_) {
    int d = dst_s[i];
    int lo = r*RNG_S;
    if (d >= lo && d < lo + RNG_S) {
      int pos = rowptr_s[d] + atomicAdd(&cursor_s[d], 1);
      srcp_s[pos] = (unsigned short)src_s[i];
    }
  } else if (i < EN_ + EV_) {
    int j = i - EN_;
    int d = dst_v[j];
    int lo = r*RNG_V;
    if (d >= lo && d < lo + RNG_V) {
      int pos = rowptr_v[d] + atomicAdd(&cursor_v[d], 1);
      srcp_v[pos] = (unsigned short)src_v[j];
    }
  }
}

// ---------- fused weight prep: W_ih transpose + 5x split ----------
__global__ __launch_bounds__(256) void k_prep(const float* W_ih, const float* Ws2,
                                              const float* Ws3, const float* W_attn,
                                              const float* Wv2, const float* Wv3,
                                              float* WTih,
                                              unsigned short* WS2hi, unsigned short* WS2lo,
                                              unsigned short* WS3hi, unsigned short* WS3lo,
                                              unsigned short* WAhi, unsigned short* WAlo,
                                              unsigned short* WV2hi, unsigned short* WV2lo,
                                              unsigned short* WV3hi, unsigned short* WV3lo) {
  int idx = blockIdx.x*256 + threadIdx.x;
  int task = blockIdx.y;
  if (task == 0) {
    if (idx < 128*384) {
      int k = idx / 384, j = idx - k*384;
      WTih[idx] = W_ih[(size_t)j*128 + k];
    }
  } else {
    if (idx >= 128*128) return;
    int j = idx >> 7, k = idx & 127;
    float v; unsigned short *hi, *lo;
    if (task == 1)      { v = Ws2[(size_t)k*128 + j];    hi = WS2hi; lo = WS2lo; }
    else if (task == 2) { v = Ws3[(size_t)k*128 + j];    hi = WS3hi; lo = WS3lo; }
    else if (task == 3) { v = W_attn[(size_t)j*256 + k]; hi = WAhi;  lo = WAlo;  }
    else if (task == 4) { v = Wv2[(size_t)k*128 + j];    hi = WV2hi; lo = WV2lo; }
    else                { v = Wv3[(size_t)k*128 + j];    hi = WV3hi; lo = WV3lo; }
    unsigned short h = bf16_rne(v);
    hi[idx] = h; lo[idx] = bf16_rne(v - bf16_tof(h));
  }
}

// ---------- static-path aggregate: masked 8-batches (no serial tail) ----------
__global__ __launch_bounds__(256) void k_aggregate_split(int nNodes, const int* __restrict__ rowptr,
    const unsigned short* __restrict__ srcp, const float* __restrict__ el, const float* __restrict__ er,
    const unsigned short* __restrict__ z, const float* __restrict__ bias,
    unsigned short* __restrict__ outHi, unsigned short* __restrict__ outLo) {
  int w = (blockIdx.x*256 + threadIdx.x) >> 6;
  int lane = threadIdx.x & 63;
  if (w >= nNodes) return;
  int beg = rowptr[w], end = rowptr[w+1];
  float erw = er[w];
  float a0 = 0.f, a1 = 0.f, wsum = 0.f;
  for (int i = beg; i < end; i += 8) {
    int sI[8]; float lv[8]; ushort2 q[8];
    #pragma unroll
    for (int u = 0; u < 8; ++u) {
      int idx = i + u; idx = (idx < end) ? idx : (end - 1);
      sI[u] = srcp[idx];
    }
    #pragma unroll
    for (int u = 0; u < 8; ++u) lv[u] = el[sI[u]];
    #pragma unroll
    for (int u = 0; u < 8; ++u) q[u] = *(const ushort2*)(z + (size_t)sI[u]*H_ + lane*2);
    #pragma unroll
    for (int u = 0; u < 8; ++u) {
      float wt = (i + u < end) ? __expf(lrelu02(lv[u] + erw)) : 0.f;
      a0 += wt*bf16_tof(q[u].x);
      a1 += wt*bf16_tof(q[u].y);
      wsum += wt;
    }
  }
  float inv = (end > beg) ? fast_rcp(wsum) : 0.f;
  float o0 = a0*inv + bias[lane*2];
  float o1 = a1*inv + bias[lane*2 + 1];
  unsigned short h0 = bf16_rne(o0), h1 = bf16_rne(o1);
  ushort2 hv; hv.x = h0; hv.y = h1;
  ushort2 lv2; lv2.x = bf16_rne(o0 - bf16_tof(h0)); lv2.y = bf16_rne(o1 - bf16_tof(h1));
  *(ushort2*)(outHi + (size_t)w*H_ + lane*2) = hv;
  *(ushort2*)(outLo + (size_t)w*H_ + lane*2) = lv2;
}

// ---------- MFMA split-bf16 GEMM: C/Cb[M,128] = (Ahi+Alo)@(Whi+Wlo), WT[col][k] ----------
__global__ __launch_bounds__(256) void k_mfma_gemm(
    const unsigned short* __restrict__ Ahi, const unsigned short* __restrict__ Alo,
    const unsigned short* __restrict__ WThi, const unsigned short* __restrict__ WTlo,
    float* __restrict__ C, unsigned short* __restrict__ Cb,
    const float* __restrict__ al, const float* __restrict__ ar,
    float* __restrict__ el, float* __restrict__ er) {
  __shared__ unsigned short lAhi[64*136];
  __shared__ unsigned short lAlo[64*136];
  __shared__ float redl[4][64];
  __shared__ float redr[4][64];
  int t = threadIdx.x;
  int row0 = blockIdx.x * 64;
  int wid = t >> 6, lane = t & 63;
  int g = lane >> 4, c = lane & 15;

  #pragma unroll
  for (int i = 0; i < 4; ++i) {
    int m = t + 256*i;
    int r = m >> 4;
    int kc = (m & 15) * 8;
    *(short8v*)(lAhi + r*136 + kc) = *(const short8v*)(Ahi + (size_t)(row0 + r)*H_ + kc);
    *(short8v*)(lAlo + r*136 + kc) = *(const short8v*)(Alo + (size_t)(row0 + r)*H_ + kc);
  }

  short8v bhi[2][4], blo[2][4];
  #pragma unroll
  for (int ct = 0; ct < 2; ++ct) {
    int col = wid*32 + ct*16 + c;
    #pragma unroll
    for (int kb = 0; kb < 4; ++kb) {
      size_t o = (size_t)col*H_ + kb*32 + g*8;
      bhi[ct][kb] = *(const short8v*)(WThi + o);
      blo[ct][kb] = *(const short8v*)(WTlo + o);
    }
  }

  floatx4 acc[4][2];
  #pragma unroll
  for (int rt = 0; rt < 4; ++rt)
    #pragma unroll
    for (int ct = 0; ct < 2; ++ct)
      acc[rt][ct] = (floatx4){0.f, 0.f, 0.f, 0.f};

  __syncthreads();

  #pragma unroll
  for (int kb = 0; kb < 4; ++kb) {
    short8v ahi[4], alo[4];
    #pragma unroll
    for (int rt = 0; rt < 4; ++rt) {
      int r = rt*16 + c;
      ahi[rt] = *(const short8v*)(lAhi + r*136 + kb*32 + g*8);
      alo[rt] = *(const short8v*)(lAlo + r*136 + kb*32 + g*8);
    }
    #pragma unroll
    for (int rt = 0; rt < 4; ++rt)
      #pragma unroll
      for (int ct = 0; ct < 2; ++ct) {
        acc[rt][ct] = __builtin_amdgcn_mfma_f32_16x16x32_bf16(ahi[rt], bhi[ct][kb], acc[rt][ct], 0, 0, 0);
        acc[rt][ct] = __builtin_amdgcn_mfma_f32_16x16x32_bf16(alo[rt], bhi[ct][kb], acc[rt][ct], 0, 0, 0);
        acc[rt][ct] = __builtin_amdgcn_mfma_f32_16x16x32_bf16(ahi[rt], blo[ct][kb], acc[rt][ct], 0, 0, 0);
      }
  }

  #pragma unroll
  for (int rt = 0; rt < 4; ++rt)
    #pragma unroll
    for (int i = 0; i < 4; ++i) {
      int row = row0 + rt*16 + g*4 + i;
      if (Cb) {
        unsigned short* cr = Cb + (size_t)row*H_ + wid*32;
        cr[c]      = bf16_rne(acc[rt][0][i]);
        cr[16 + c] = bf16_rne(acc[rt][1][i]);
      } else {
        float* cr = C + (size_t)row*H_ + wid*32;
        cr[c]      = acc[rt][0][i];
        cr[16 + c] = acc[rt][1][i];
      }
    }

  if (el) {
    float av0 = al[wid*32 + c], av1 = al[wid*32 + 16 + c];
    float rv0 = ar[wid*32 + c], rv1 = ar[wid*32 + 16 + c];
    #pragma unroll
    for (int rt = 0; rt < 4; ++rt)
      #pragma unroll
      for (int i = 0; i < 4; ++i) {
        float pl = acc[rt][0][i]*av0 + acc[rt][1][i]*av1;
        float pr = acc[rt][0][i]*rv0 + acc[rt][1][i]*rv1;
        pl += __shfl_xor(pl, 1, 64); pl += __shfl_xor(pl, 2, 64);
        pl += __shfl_xor(pl, 4, 64); pl += __shfl_xor(pl, 8, 64);
        pr += __shfl_xor(pr, 1, 64); pr += __shfl_xor(pr, 2, 64);
        pr += __shfl_xor(pr, 4, 64); pr += __shfl_xor(pr, 8, 64);
        if (c == 0) { redl[wid][rt*16 + g*4 + i] = pl; redr[wid][rt*16 + g*4 + i] = pr; }
      }
    __syncthreads();
    if (t < 64) {
      el[row0 + t] = redl[0][t] + redl[1][t] + redl[2][t] + redl[3][t];
      er[row0 + t] = redr[0][t] + redr[1][t] + redr[2][t] + redr[3][t];
    }
  }
}

// ---------- FUSED A1-MFMA + attention: pi computed from accs, no Z round-trip ----------
__global__ __launch_bounds__(256) void k_mfma_attn(
    const unsigned short* __restrict__ Ahi, const unsigned short* __restrict__ Alo,
    const unsigned short* __restrict__ WThi, const unsigned short* __restrict__ WTlo,
    const float* __restrict__ A2, const float* __restrict__ v_attn,
    const int* __restrict__ vnr_VNF, const int* __restrict__ net_VNF,
    float* __restrict__ pi) {
  __shared__ unsigned short lAhi[64*136];
  __shared__ unsigned short lAlo[64*136];
  __shared__ float a2s2[2][10][128];   // 2*A2 for up to 2 batches this block spans
  __shared__ float vv2s[128];          // 2*v
  __shared__ float part[64][10];       // per-(row,s) partial sums (LDS atomics)
  __shared__ float vsumLds;
  int t = threadIdx.x;
  int row0 = blockIdx.x * 64;
  int wid = t >> 6, lane = t & 63;
  int g = lane >> 4, c = lane & 15;
  int b0 = row0 / NN_;
  int b1 = (row0 + 63) / NN_; if (b1 > B_-1) b1 = B_-1;

  #pragma unroll
  for (int i = 0; i < 4; ++i) {
    int m = t + 256*i;
    int r = m >> 4;
    int kc = (m & 15) * 8;
    *(short8v*)(lAhi + r*136 + kc) = *(const short8v*)(Ahi + (size_t)(row0 + r)*H_ + kc);
    *(short8v*)(lAlo + r*136 + kc) = *(const short8v*)(Alo + (size_t)(row0 + r)*H_ + kc);
  }
  // stage 2*A2 for both candidate batches (each slab is 10*128=1280 floats)
  for (int i = t; i < 2560; i += 256) {
    int w = (i >= 1280) ? 1 : 0;
    int rem = i - w*1280;
    int s = rem >> 7, k = rem & 127;
    int b = (w == 0) ? b0 : b1;
    a2s2[w][s][k] = 2.f*A2[((size_t)s*B_ + b)*H_ + k];
  }
  if (t < 128) vv2s[t] = 2.f*v_attn[t];
  for (int o = t; o < 640; o += 256) ((float*)part)[o] = 0.f;

  short8v bhi[2][4], blo[2][4];
  #pragma unroll
  for (int ct = 0; ct < 2; ++ct) {
    int col = wid*32 + ct*16 + c;
    #pragma unroll
    for (int kb = 0; kb < 4; ++kb) {
      size_t o = (size_t)col*H_ + kb*32 + g*8;
      bhi[ct][kb] = *(const short8v*)(WThi + o);
      blo[ct][kb] = *(const short8v*)(WTlo + o);
    }
  }

  floatx4 acc[4][2];
  #pragma unroll
  for (int rt = 0; rt < 4; ++rt)
    #pragma unroll
    for (int ct = 0; ct < 2; ++ct)
      acc[rt][ct] = (floatx4){0.f, 0.f, 0.f, 0.f};

  __syncthreads();

  if (t == 0) {
    float s = 0.f;
    for (int k = 0; k < 128; ++k) s += vv2s[k];
    vsumLds = 0.5f*s;
  }

  #pragma unroll
  for (int kb = 0; kb < 4; ++kb) {
    short8v ahi[4], alo[4];
    #pragma unroll
    for (int rt = 0; rt < 4; ++rt) {
      int r = rt*16 + c;
      ahi[rt] = *(const short8v*)(lAhi + r*136 + kb*32 + g*8);
      alo[rt] = *(const short8v*)(lAlo + r*136 + kb*32 + g*8);
    }
    #pragma unroll
    for (int rt = 0; rt < 4; ++rt)
      #pragma unroll
      for (int ct = 0; ct < 2; ++ct) {
        acc[rt][ct] = __builtin_amdgcn_mfma_f32_16x16x32_bf16(ahi[rt], bhi[ct][kb], acc[rt][ct], 0, 0, 0);
        acc[rt][ct] = __builtin_amdgcn_mfma_f32_16x16x32_bf16(alo[rt], bhi[ct][kb], acc[rt][ct], 0, 0, 0);
        acc[rt][ct] = __builtin_amdgcn_mfma_f32_16x16x32_bf16(ahi[rt], blo[ct][kb], acc[rt][ct], 0, 0, 0);
      }
  }

  // attention: thread's 2 cols (wid*32+c, wid*32+16+c) x 16 rows x 10 steps
  float v0 = vv2s[wid*32 + c], v1 = vv2s[wid*32 + 16 + c];
  #pragma unroll
  for (int rt = 0; rt < 4; ++rt)
    #pragma unroll
    for (int i = 0; i < 4; ++i) {
      int lrow = rt*16 + g*4 + i;
      int w = ((row0 + lrow) >= (b0+1)*NN_ && b1 != b0) ? 1 : 0;
      float a1c0 = acc[rt][0][i], a1c1 = acc[rt][1][i];
      #pragma unroll
      for (int s = 0; s < 10; ++s) {
        float a20 = a2s2[w][s][wid*32 + c];
        float a21 = a2s2[w][s][wid*32 + 16 + c];
        float t0 = fast_rcp(1.f + __expf(fmaf(2.f, a1c0, a20)));
        float t1 = fast_rcp(1.f + __expf(fmaf(2.f, a1c1, a21)));
        atomicAdd(&part[lrow][s], v0*t0 + v1*t1);
      }
    }
  __syncthreads();

  float vsum = vsumLds;
  for (int o = t; o < 640; o += 256) {
    int lrow = o/10, s = o - lrow*10;
    int row = row0 + lrow;
    int b = row / NN_, n = row - b*NN_;
    int vnf = vnr_VNF[b*NV_ + s];
    int m   = net_VNF[(size_t)row*T_ + vnf];
    pi[(size_t)b*(NV_*NN_) + (size_t)s*NN_ + n] = vsum - part[lrow][s] + __logf((float)m);
  }
}

// ---------- FUSED aggregate -> MFMA GEMM (vnr path only: 10 blocks, tiny) ----------
__global__ __launch_bounds__(256) void k_agg_mfma(
    const int* __restrict__ rowptr, const unsigned short* __restrict__ srcp,
    const float* __restrict__ el_in, const float* __restrict__ er_in,
    const unsigned short* __restrict__ z_in, const float* __restrict__ bias,
    const unsigned short* __restrict__ WThi, const unsigned short* __restrict__ WTlo,
    unsigned short* __restrict__ zb_out, float* __restrict__ Cf,
    const float* __restrict__ al, const float* __restrict__ ar,
    float* __restrict__ el_out, float* __restrict__ er_out) {
  __shared__ unsigned short lAhi[64*136];
  __shared__ unsigned short lAlo[64*136];
  __shared__ float redl[4][64];
  __shared__ float redr[4][64];
  int t = threadIdx.x;
  int row0 = blockIdx.x * 64;
  int wid = t >> 6, lane = t & 63;
  int g = lane >> 4, c = lane & 15;

  float b0 = bias[lane*2], b1 = bias[lane*2 + 1];

  for (int j = 0; j < 8; ++j) {
    int wA = row0 + wid*16 + 2*j;
    int wB = wA + 1;
    int begA = rowptr[wA], endA = rowptr[wA+1];
    int begB = rowptr[wB], endB = rowptr[wB+1];
    float erA = er_in[wA], erB = er_in[wB];
    float a0A = 0.f, a1A = 0.f, wsA = 0.f;
    float a0B = 0.f, a1B = 0.f, wsB = 0.f;
    int iA = begA, iB = begB;
    while (iA < endA || iB < endB) {
      int sA[8], sB[8];
      #pragma unroll
      for (int u = 0; u < 8; ++u) {
        sA[u] = (iA + u < endA) ? (int)srcp[iA + u] : 0;
        sB[u] = (iB + u < endB) ? (int)srcp[iB + u] : 0;
      }
      float lA[8], lB[8];
      #pragma unroll
      for (int u = 0; u < 8; ++u) { lA[u] = el_in[sA[u]]; lB[u] = el_in[sB[u]]; }
      ushort2 qA[8], qB[8];
      #pragma unroll
      for (int u = 0; u < 8; ++u) {
        qA[u] = *(const ushort2*)(z_in + (size_t)sA[u]*H_ + lane*2);
        qB[u] = *(const ushort2*)(z_in + (size_t)sB[u]*H_ + lane*2);
      }
      #pragma unroll
      for (int u = 0; u < 8; ++u) {
        float wtA = (iA + u < endA) ? __expf(lrelu02(lA[u] + erA)) : 0.f;
        float wtB = (iB + u < endB) ? __expf(lrelu02(lB[u] + erB)) : 0.f;
        a0A += wtA*bf16_tof(qA[u].x); a1A += wtA*bf16_tof(qA[u].y); wsA += wtA;
        a0B += wtB*bf16_tof(qB[u].x); a1B += wtB*bf16_tof(qB[u].y); wsB += wtB;
      }
      iA += 8; iB += 8;
    }
    float invA = (endA > begA) ? fast_rcp(wsA) : 0.f;
    float invB = (endB > begB) ? fast_rcp(wsB) : 0.f;
    float o0A = a0A*invA + b0, o1A = a1A*invA + b1;
    float o0B = a0B*invB + b0, o1B = a1B*invB + b1;
    int rA = wid*16 + 2*j;
    unsigned short hA0 = bf16_rne(o0A), hA1 = bf16_rne(o1A);
    unsigned short hB0 = bf16_rne(o0B), hB1 = bf16_rne(o1B);
    ushort2 hvA; hvA.x = hA0; hvA.y = hA1;
    ushort2 lvA; lvA.x = bf16_rne(o0A - bf16_tof(hA0)); lvA.y = bf16_rne(o1A - bf16_tof(hA1));
    ushort2 hvB; hvB.x = hB0; hvB.y = hB1;
    ushort2 lvB; lvB.x = bf16_rne(o0B - bf16_tof(hB0)); lvB.y = bf16_rne(o1B - bf16_tof(hB1));
    *(ushort2*)(lAhi + rA*136 + lane*2) = hvA;
    *(ushort2*)(lAlo + rA*136 + lane*2) = lvA;
    *(ushort2*)(lAhi + (rA+1)*136 + lane*2) = hvB;
    *(ushort2*)(lAlo + (rA+1)*136 + lane*2) = lvB;
  }

  short8v bhi[2][4], blo[2][4];
  #pragma unroll
  for (int ct = 0; ct < 2; ++ct) {
    int col = wid*32 + ct*16 + c;
    #pragma unroll
    for (int kb = 0; kb < 4; ++kb) {
      size_t o = (size_t)col*H_ + kb*32 + g*8;
      bhi[ct][kb] = *(const short8v*)(WThi + o);
      blo[ct][kb] = *(const short8v*)(WTlo + o);
    }
  }

  floatx4 acc[4][2];
  #pragma unroll
  for (int rt = 0; rt < 4; ++rt)
    #pragma unroll
    for (int ct = 0; ct < 2; ++ct)
      acc[rt][ct] = (floatx4){0.f, 0.f, 0.f, 0.f};

  __syncthreads();

  #pragma unroll
  for (int kb = 0; kb < 4; ++kb) {
    short8v ahi[4], alo[4];
    #pragma unroll
    for (int rt = 0; rt < 4; ++rt) {
      int r = rt*16 + c;
      ahi[rt] = *(const short8v*)(lAhi + r*136 + kb*32 + g*8);
      alo[rt] = *(const short8v*)(lAlo + r*136 + kb*32 + g*8);
    }
    #pragma unroll
    for (int rt = 0; rt < 4; ++rt)
      #pragma unroll
      for (int ct = 0; ct < 2; ++ct) {
        acc[rt][ct] = __builtin_amdgcn_mfma_f32_16x16x32_bf16(ahi[rt], bhi[ct][kb], acc[rt][ct], 0, 0, 0);
        acc[rt][ct] = __builtin_amdgcn_mfma_f32_16x16x32_bf16(alo[rt], bhi[ct][kb], acc[rt][ct], 0, 0, 0);
        acc[rt][ct] = __builtin_amdgcn_mfma_f32_16x16x32_bf16(ahi[rt], blo[ct][kb], acc[rt][ct], 0, 0, 0);
      }
  }

  #pragma unroll
  for (int rt = 0; rt < 4; ++rt)
    #pragma unroll
    for (int i = 0; i < 4; ++i) {
      int row = row0 + rt*16 + g*4 + i;
      if (zb_out) {
        unsigned short* cr = zb_out + (size_t)row*H_ + wid*32;
        cr[c]      = bf16_rne(acc[rt][0][i]);
        cr[16 + c] = bf16_rne(acc[rt][1][i]);
      } else {
        float* cr = Cf + (size_t)row*H_ + wid*32;
        cr[c]      = acc[rt][0][i];
        cr[16 + c] = acc[rt][1][i];
      }
    }

  if (el_out) {
    float av0 = al[wid*32 + c], av1 = al[wid*32 + 16 + c];
    float rv0 = ar[wid*32 + c], rv1 = ar[wid*32 + 16 + c];
    #pragma unroll
    for (int rt = 0; rt < 4; ++rt)
      #pragma unroll
      for (int i = 0; i < 4; ++i) {
        float pl = acc[rt][0][i]*av0 + acc[rt][1][i]*av1;
        float pr = acc[rt][0][i]*rv0 + acc[rt][1][i]*rv1;
        pl += __shfl_xor(pl, 1, 64); pl += __shfl_xor(pl, 2, 64);
        pl += __shfl_xor(pl, 4, 64); pl += __shfl_xor(pl, 8, 64);
        pr += __shfl_xor(pr, 1, 64); pr += __shfl_xor(pr, 2, 64);
        pr += __shfl_xor(pr, 4, 64); pr += __shfl_xor(pr, 8, 64);
        if (c == 0) { redl[wid][rt*16 + g*4 + i] = pl; redr[wid][rt*16 + g*4 + i] = pr; }
      }
    __syncthreads();
    if (t < 64) {
      el_out[row0 + t] = redl[0][t] + redl[1][t] + redl[2][t] + redl[3][t];
      er_out[row0 + t] = redr[0][t] + redr[1][t] + redr[2][t] + redr[3][t];
    }
  }
}

// ---------- plain aggregate: bf16 z in, f32 out (vnr layer 3) ----------
__global__ __launch_bounds__(256) void k_aggregate_f(int nNodes, const int* __restrict__ rowptr,
    const unsigned short* __restrict__ srcp, const float* __restrict__ el,
    const float* __restrict__ er, const unsigned short* __restrict__ z,
    const float* __restrict__ bias, float* __restrict__ out) {
  int w = (blockIdx.x*256 + threadIdx.x) >> 6;
  int lane = threadIdx.x & 63;
  if (w >= nNodes) return;
  int beg = rowptr[w], end = rowptr[w+1];
  float erw = er[w];
  float a0 = 0.f, a1 = 0.f, wsum = 0.f;
  for (int i = beg; i < end; ++i) {
    int sI = srcp[i];
    float wt = __expf(lrelu02(el[sI] + erw));
    ushort2 q = *(const ushort2*)(z + (size_t)sI*H_ + lane*2);
    a0 += wt*bf16_tof(q.x); a1 += wt*bf16_tof(q.y); wsum += wt;
  }
  float inv = (end > beg) ? fast_rcp(wsum) : 0.f;
  float2 o;
  o.x = a0*inv + bias[lane*2];
  o.y = a1*inv + bias[lane*2 + 1];
  *(float2*)(out + (size_t)w*H_ + lane*2) = o;
}

// ---------- generic f32 GEMM (layer-1 static, layer-1 vnr, GI) ----------
__global__ __launch_bounds__(256) void k_gemm(const float* A, int M, int K, int N,
                                              const float* W, const float* bias,
                                              float* C, unsigned short* Cb,
                                              const float* al, const float* ar,
                                              float* el, float* er) {
  __shared__ float Ws_[64*128];
  __shared__ float As_[16*128];
  __shared__ float redl[16][17];
  __shared__ float redr[16][17];
  int t = threadIdx.x;
  int j0 = blockIdx.y * 128;
  int row0 = blockIdx.x * 16;
  for (int l = t; l < 16*K; l += 256) {
    int r = l / K, k = l - r*K;
    int row = row0 + r;
    As_[r*K + k] = (row < M) ? A[(size_t)row*K + k] : 0.f;
  }
  int jg = t & 15, r = t >> 4;
  float acc[8];
  #pragma unroll
  for (int q = 0; q < 8; ++q) acc[q] = 0.f;
  for (int kc = 0; kc < K; kc += 64) {
    int kl = min(64, K - kc);
    __syncthreads();
    for (int l = t; l < (kl << 7); l += 256) {
      int k = l >> 7, j = l & 127;
      int jj = j0 + j;
      Ws_[l] = (jj < N) ? W[(size_t)(kc + k)*N + jj] : 0.f;
    }
    __syncthreads();
    for (int k = 0; k < kl; ++k) {
      float a = As_[r*K + kc + k];
      const float* wr = &Ws_[(k << 7) + jg*8];
      #pragma unroll
      for (int q = 0; q < 8; ++q) acc[q] += a * wr[q];
    }
  }
  int row = row0 + r;
  if (row < M) {
    if (Cb) {
      unsigned short* crow = Cb + (size_t)row*N + j0 + jg*8;
      #pragma unroll
      for (int q = 0; q < 8; ++q) {
        int j = j0 + jg*8 + q;
        if (j < N) crow[q] = bf16_rne(acc[q] + (bias ? bias[j] : 0.f));
      }
    } else {
      float* crow = C + (size_t)row*N + j0 + jg*8;
      #pragma unroll
      for (int q = 0; q < 8; ++q) {
        int j = j0 + jg*8 + q;
        if (j < N) crow[q] = acc[q] + (bias ? bias[j] : 0.f);
      }
    }
  }
  if (el) {
    float pl = 0.f, pr = 0.f;
    #pragma unroll
    for (int q = 0; q < 8; ++q) {
      int j = jg*8 + q;
      pl += acc[q]*al[j];
      pr += acc[q]*ar[j];
    }
    redl[r][jg] = pl; redr[r][jg] = pr;
    __syncthreads();
    if (t < 16) {
      float sl = 0.f, sr = 0.f;
      for (int q = 0; q < 16; ++q) { sl += redl[t][q]; sr += redr[t][q]; }
      int row2 = row0 + t;
      if (row2 < M) { el[row2] = sl; er[row2] = sr; }
    }
  }
}

// ---------- GRU decoder: weights register-resident, LDS-broadcast h ----------
__global__ __launch_bounds__(512) void k_decoder(const float* __restrict__ GI,
                                                 const float* __restrict__ W_hh,
                                                 const float* __restrict__ b_hh,
                                                 const float* __restrict__ W_attn,
                                                 const float* __restrict__ h0,
                                                 float* __restrict__ A2) {
  int b = blockIdx.x;
  __shared__ float h[128];
  __shared__ float gh[384];
  int t = threadIdx.x;
  const float4* wsrc = (t < 384)
      ? (const float4*)(W_hh + (size_t)t*128)
      : (const float4*)(W_attn + (size_t)(t-384)*256 + 128);
  float4 wreg[32];
  #pragma unroll
  for (int kk = 0; kk < 32; ++kk) wreg[kk] = wsrc[kk];
  float bh = (t < 384) ? b_hh[t] : 0.f;
  if (t < 128) h[t] = h0[t];
  __syncthreads();
  for (int s = 0; s < 10; ++s) {
    const float4* h4 = (const float4*)h;
    if (t < 384) {
      float a0 = 0.f, a1 = 0.f, a2 = 0.f, a3 = 0.f;
      #pragma unroll
      for (int kk = 0; kk < 32; kk += 4) {
        a0 += dot4(wreg[kk+0], h4[kk+0]);
        a1 += dot4(wreg[kk+1], h4[kk+1]);
        a2 += dot4(wreg[kk+2], h4[kk+2]);
        a3 += dot4(wreg[kk+3], h4[kk+3]);
      }
      gh[t] = (a0 + a1) + (a2 + a3) + bh;
    }
    __syncthreads();
    if (t < 128) {
      const float* gi = GI + (size_t)(b*NV_ + s)*384;
      float rr = fast_sigmoid(gi[t]       + gh[t]);
      float zz = fast_sigmoid(gi[128 + t] + gh[128 + t]);
      float nn = fast_tanh   (gi[256 + t] + rr*gh[256 + t]);
      h[t] = (1.f - zz)*nn + zz*h[t];
    }
    __syncthreads();
    if (t >= 384) {
      float a0 = 0.f, a1 = 0.f, a2 = 0.f, a3 = 0.f;
      #pragma unroll
      for (int kk = 0; kk < 32; kk += 4) {
        a0 += dot4(wreg[kk+0], h4[kk+0]);
        a1 += dot4(wreg[kk+1], h4[kk+1]);
        a2 += dot4(wreg[kk+2], h4[kk+2]);
        a3 += dot4(wreg[kk+3], h4[kk+3]);
      }
      A2[((size_t)s*B_ + b)*128 + (t - 384)] = (a0 + a1) + (a2 + a3);
    }
  }
}

// ---------- value head ----------
__global__ __launch_bounds__(128) void k_y2s(const unsigned short* hi, const unsigned short* lo,
                                             float* y2) {
  int b = blockIdx.x, slice = blockIdx.y, h = threadIdx.x;
  int n0 = slice*125, n1 = n0 + 125;
  float s = 0.f;
  for (int n = n0; n < n1; ++n) {
    size_t idx = ((size_t)b*NN_ + n)*H_ + h;
    s += bf16_tof(hi[idx]) + bf16_tof(lo[idx]);
  }
  atomicAdd(&y2[b*H_ + h], s);
}

__global__ __launch_bounds__(128) void k_value(const float* __restrict__ Hv,
                                               const float* __restrict__ nmask,
                                               const float* __restrict__ y2,
                                               const float* __restrict__ W_out,
                                               const float* __restrict__ b_out,
                                               float* __restrict__ val) {
  __shared__ float y1s[128];
  int b = blockIdx.x, t = threadIdx.x;
  float s = 0.f, d = 0.f;
  #pragma unroll
  for (int i = 0; i < NV_; ++i) {
    float m = nmask[b*NV_ + i];
    s += Hv[(size_t)(b*NV_ + i)*H_ + t]*m;
    d += m;
  }
  y1s[t] = s/d;
  __syncthreads();
  if (t < 64) {
    const float* w = W_out + (size_t)t*256;
    float acc = b_out[t];
    for (int h = 0; h < H_; ++h)
      acc += y1s[h]*w[h] + (y2[b*H_ + h]*(1.f/1000.f))*w[128 + h];
    val[b*O_ + t] = acc;
  }
}

extern "C" void kernel_launch(void* const* d_in, const int* in_sizes, int n_in,
                              void* d_out, int out_size, void* d_ws, size_t ws_size,
                              hipStream_t stream) {
  (void)in_sizes; (void)n_in; (void)out_size; (void)ws_size;
  const float* static_feat = (const float*)d_in[0];
  const float* vnr_feat    = (const float*)d_in[1];
  const float* nmask       = (const float*)d_in[2];
  const float* Ws1 = (const float*)d_in[3];  const float* als1 = (const float*)d_in[4];
  const float* ars1 = (const float*)d_in[5]; const float* bs1 = (const float*)d_in[6];
  const float* Ws2 = (const float*)d_in[7];  const float* als2 = (const float*)d_in[8];
  const float* ars2 = (const float*)d_in[9]; const float* bs2 = (const float*)d_in[10];
  const float* Ws3 = (const float*)d_in[11]; const float* als3 = (const float*)d_in[12];
  const float* ars3 = (const float*)d_in[13]; const float* bs3 = (const float*)d_in[14];
  const float* Wv1 = (const float*)d_in[15]; const float* alv1 = (const float*)d_in[16];
  const float* arv1 = (const float*)d_in[17]; const float* bv1 = (const float*)d_in[18];
  const float* Wv2 = (const float*)d_in[19]; const float* alv2 = (const float*)d_in[20];
  const float* arv2 = (const float*)d_in[21]; const float* bv2 = (const float*)d_in[22];
  const float* Wv3 = (const float*)d_in[23]; const float* alv3 = (const float*)d_in[24];
  const float* arv3 = (const float*)d_in[25]; const float* bv3 = (const float*)d_in[26];
  const float* W_attn = (const float*)d_in[27];
  const float* v_attn = (const float*)d_in[28];
  const float* W_ih = (const float*)d_in[29];
  const float* W_hh = (const float*)d_in[30];
  const float* b_ih = (const float*)d_in[31];
  const float* b_hh = (const float*)d_in[32];
  const float* h0   = (const float*)d_in[33];
  const float* W_out = (const float*)d_in[34];
  const float* b_out = (const float*)d_in[35];
  const int* src_s = (const int*)d_in[36];
  const int* dst_s = (const int*)d_in[37];
  const int* src_v = (const int*)d_in[38];
  const int* dst_v = (const int*)d_in[39];
  const int* vnr_VNF = (const int*)d_in[40];
  const int* net_VNF = (const int*)d_in[41];

  char* ws = (char*)d_ws;
  size_t off = 0;
  auto alloc = [&](size_t bytes) -> char* {
    off = (off + 255) & ~(size_t)255;
    char* p = ws + off;
    off += bytes;
    return p;
  };
  unsigned short* Zb0 = (unsigned short*)alloc((size_t)NS_*H_*2);   // bf16 z
  unsigned short* HsHi = (unsigned short*)alloc((size_t)NS_*H_*2);
  unsigned short* HsLo = (unsigned short*)alloc((size_t)NS_*H_*2);
  unsigned short* Zbv0 = (unsigned short*)alloc((size_t)NVT_*H_*2);
  unsigned short* Zbv1 = (unsigned short*)alloc((size_t)NVT_*H_*2);
  float* Hv   = (float*)alloc((size_t)NVT_*H_*4);
  float* el_s = (float*)alloc((size_t)NS_*4);
  float* er_s = (float*)alloc((size_t)NS_*4);
  float* elv_a = (float*)alloc((size_t)NVT_*4);
  float* erv_a = (float*)alloc((size_t)NVT_*4);
  float* elv_b = (float*)alloc((size_t)NVT_*4);
  float* erv_b = (float*)alloc((size_t)NVT_*4);
  size_t zcount = (size_t)NS_ + NS_ + NVT_ + NVT_ + B_*H_;
  char* zb = alloc(zcount*4);
  int*   counts_s = (int*)zb;
  int*   cursor_s = counts_s + NS_;
  int*   counts_v = cursor_s + NS_;
  int*   cursor_v = counts_v + NVT_;
  float* y2buf    = (float*)(cursor_v + NVT_);
  int* rowptr_s = (int*)alloc((size_t)(NS_+1)*4);
  int* rowptr_v = (int*)alloc((size_t)(NVT_+1)*4);
  int* bsum     = (int*)alloc((size_t)256*4);
  unsigned short* srcp_s = (unsigned short*)alloc((size_t)(EN_+8)*2);
  unsigned short* srcp_v = (unsigned short*)alloc((size_t)(EV_+8)*2);
  unsigned short* WS2hi = (unsigned short*)alloc((size_t)H_*H_*2);
  unsigned short* WS2lo = (unsigned short*)alloc((size_t)H_*H_*2);
  unsigned short* WS3hi = (unsigned short*)alloc((size_t)H_*H_*2);
  unsigned short* WS3lo = (unsigned short*)alloc((size_t)H_*H_*2);
  unsigned short* WAhi  = (unsigned short*)alloc((size_t)H_*H_*2);
  unsigned short* WAlo  = (unsigned short*)alloc((size_t)H_*H_*2);
  unsigned short* WV2hi = (unsigned short*)alloc((size_t)H_*H_*2);
  unsigned short* WV2lo = (unsigned short*)alloc((size_t)H_*H_*2);
  unsigned short* WV3hi = (unsigned short*)alloc((size_t)H_*H_*2);
  unsigned short* WV3lo = (unsigned short*)alloc((size_t)H_*H_*2);
  float* WTih   = (float*)alloc((size_t)H_*384*4);
  float* GI     = (float*)alloc((size_t)NVT_*384*4);
  float* A2     = (float*)alloc((size_t)NV_*B_*H_*4);

  float* pi  = (float*)d_out;
  float* val = pi + (size_t)B_*NV_*NN_;

  hipMemsetAsync(zb, 0, zcount*4, stream);

  k_prep<<<dim3(192, 6), 256, 0, stream>>>(W_ih, Ws2, Ws3, W_attn, Wv2, Wv3, WTih,
                                           WS2hi, WS2lo, WS3hi, WS3lo, WAhi, WAlo,
                                           WV2hi, WV2lo, WV3hi, WV3lo);

  // CSR build: XCD-ranged count + scatter
  int edgeChunks = (EN_ + EV_ + 255)/256;
  k_count_r<<<edgeChunks*8, 256, 0, stream>>>(dst_s, dst_v, counts_s, counts_v);
  k_scan_local<<<250, 256, 0, stream>>>(counts_s, NS_, rowptr_s, bsum);
  k_scan_small<<<2, 1024, 0, stream>>>(bsum, 250, counts_v, rowptr_v, NVT_);
  k_scan_add<<<250, 256, 0, stream>>>(rowptr_s, bsum, NS_, EN_);
  k_scatter_r<<<edgeChunks*8, 256, 0, stream>>>(src_s, dst_s, src_v, dst_v,
                                                rowptr_s, rowptr_v, cursor_s, cursor_v,
                                                srcp_s, srcp_v);

  int aggS = (NS_ + 3)/4;

  // ---- static GAT stack ----
  k_gemm<<<dim3(NS_/16, 1), 256, 0, stream>>>(static_feat, NS_, FS_, H_, Ws1, nullptr,
                                              nullptr, Zb0, als1, ars1, el_s, er_s);
  k_aggregate_split<<<aggS, 256, 0, stream>>>(NS_, rowptr_s, srcp_s, el_s, er_s, Zb0, bs1, HsHi, HsLo);
  k_mfma_gemm<<<NS_/64, 256, 0, stream>>>(HsHi, HsLo, WS2hi, WS2lo, nullptr, Zb0, als2, ars2, el_s, er_s);
  k_aggregate_split<<<aggS, 256, 0, stream>>>(NS_, rowptr_s, srcp_s, el_s, er_s, Zb0, bs2, HsHi, HsLo);
  k_mfma_gemm<<<NS_/64, 256, 0, stream>>>(HsHi, HsLo, WS3hi, WS3lo, nullptr, Zb0, als3, ars3, el_s, er_s);
  k_aggregate_split<<<aggS, 256, 0, stream>>>(NS_, rowptr_s, srcp_s, el_s, er_s, Zb0, bs3, HsHi, HsLo);
  k_y2s<<<dim3(B_, 8), 128, 0, stream>>>(HsHi, HsLo, y2buf);

  // ---- vnr GAT stack (tiny: fused agg+GEMM, 10 blocks) ----
  k_gemm<<<dim3(NVT_/16, 1), 256, 0, stream>>>(vnr_feat, NVT_, FV_, H_, Wv1, nullptr,
                                               nullptr, Zbv0, alv1, arv1, elv_a, erv_a);
  k_agg_mfma<<<NVT_/64, 256, 0, stream>>>(rowptr_v, srcp_v, elv_a, erv_a, Zbv0, bv1,
                                          WV2hi, WV2lo, Zbv1, nullptr,
                                          alv2, arv2, elv_b, erv_b);
  k_agg_mfma<<<NVT_/64, 256, 0, stream>>>(rowptr_v, srcp_v, elv_b, erv_b, Zbv1, bv2,
                                          WV3hi, WV3lo, Zbv0, nullptr,
                                          alv3, arv3, elv_a, erv_a);
  k_aggregate_f<<<(NVT_ + 3)/4, 256, 0, stream>>>(NVT_, rowptr_v, srcp_v, elv_a, erv_a,
                                                  Zbv0, bv3, Hv);

  // ---- decoder ----
  k_gemm<<<dim3(NVT_/16, 3), 256, 0, stream>>>(Hv, NVT_, H_, 384, WTih, b_ih, GI, nullptr,
                                               nullptr, nullptr, nullptr, nullptr);
  k_decoder<<<B_, 512, 0, stream>>>(GI, W_hh, b_hh, W_attn, h0, A2);
  // fused A1-MFMA + attention (replaces A1 GEMM + attn3, no Z round trip)
  k_mfma_attn<<<NS_/64, 256, 0, stream>>>(HsHi, HsLo, WAhi, WAlo, A2, v_attn,
                                          vnr_VNF, net_VNF, pi);

  // ---- value head ----
  k_value<<<B_, 128, 0, stream>>>(Hv, nmask, y2buf, W_out, b_out, val);
}

// Round 14
// 404.581 us; speedup vs baseline: 1.6222x; 1.6222x over previous
//
#include <hip/hip_runtime.h>
#include <hip/hip_bf16.h>
#include <math.h>

#define B_   64
#define NN_  1000
#define NV_  10
#define H_   128
#define FS_  8
#define FV_  6
#define T_   8
#define O_   64
#define EN_  512000
#define EV_  2560
#define NS_  (B_*NN_)   /* 64000 */
#define NVT_ (B_*NV_)   /* 640 */
#define RNG_S (NS_/8)   /* 8000 dst nodes per XCD range */
#define RNG_V (NVT_/8)  /* 80 */

typedef __attribute__((ext_vector_type(8))) short short8v;   // 8 bf16
typedef __attribute__((ext_vector_type(4))) float floatx4;

__device__ __forceinline__ float fast_rcp(float x) { return __builtin_amdgcn_rcpf(x); }
__device__ __forceinline__ float fast_tanh(float x) {
  return 1.f - 2.f*fast_rcp(1.f + __expf(2.f*x));
}
__device__ __forceinline__ float fast_sigmoid(float x) {
  return fast_rcp(1.f + __expf(-x));
}
__device__ __forceinline__ unsigned short bf16_rne(float x) {
  unsigned u = __float_as_uint(x);
  return (unsigned short)((u + 0x7FFFu + ((u >> 16) & 1u)) >> 16);
}
__device__ __forceinline__ float bf16_tof(unsigned short b) {
  return __uint_as_float(((unsigned)b) << 16);
}
__device__ __forceinline__ float dot4(float4 a, float4 b) {
  return a.x*b.x + a.y*b.y + a.z*b.z + a.w*b.w;
}
__device__ __forceinline__ float lrelu02(float e) {
  return (e > 0.f) ? e : 0.2f*e;
}

// ---------- CSR build: XCD-ranged count (atomics stay in one XCD's L2) ----------
__global__ __launch_bounds__(256) void k_count_r(const int* __restrict__ dst_s,
                                                 const int* __restrict__ dst_v,
                                                 int* __restrict__ counts_s,
                                                 int* __restrict__ counts_v) {
  int bid = blockIdx.x;
  int r = bid & 7;
  int i = (bid >> 3)*256 + threadIdx.x;
  if (i < EN_) {
    int d = dst_s[i];
    int lo = r*RNG_S;
    if (d >= lo && d < lo + RNG_S) atomicAdd(&counts_s[d], 1);
  } else if (i < EN_ + EV_) {
    int d = dst_v[i - EN_];
    int lo = r*RNG_V;
    if (d >= lo && d < lo + RNG_V) atomicAdd(&counts_v[d], 1);
  }
}

__global__ __launch_bounds__(256) void k_scan_local(const int* cnt, int n, int* out, int* bsum) {
  __shared__ int s[256];
  int t = threadIdx.x; int i = blockIdx.x*256 + t;
  int v = (i < n) ? cnt[i] : 0;
  s[t] = v; __syncthreads();
  #pragma unroll
  for (int o = 1; o < 256; o <<= 1) {
    int u = (t >= o) ? s[t-o] : 0; __syncthreads();
    s[t] += u; __syncthreads();
  }
  if (i < n) out[i] = s[t] - v;
  if (t == 255) bsum[blockIdx.x] = s[255];
}

__global__ __launch_bounds__(1024) void k_scan_small(int* bsum, int nb,
                                                     const int* cntv, int* rowptr_v, int nv) {
  __shared__ int sums[1024];
  int t = threadIdx.x;
  if (blockIdx.x == 0) {
    int v = (t < nb) ? bsum[t] : 0;
    sums[t] = v; __syncthreads();
    for (int o = 1; o < 1024; o <<= 1) {
      int u = (t >= o) ? sums[t-o] : 0; __syncthreads();
      sums[t] += u; __syncthreads();
    }
    if (t < nb) bsum[t] = sums[t] - v;
  } else {
    int v = (t < nv) ? cntv[t] : 0;
    sums[t] = v; __syncthreads();
    for (int o = 1; o < 1024; o <<= 1) {
      int u = (t >= o) ? sums[t-o] : 0; __syncthreads();
      sums[t] += u; __syncthreads();
    }
    if (t < nv) rowptr_v[t] = sums[t] - v;
    if (t == nv-1) rowptr_v[nv] = sums[t];
  }
}

__global__ __launch_bounds__(256) void k_scan_add(int* out, const int* bsum, int n, int E) {
  int i = blockIdx.x*256 + threadIdx.x;
  if (i < n) out[i] += bsum[blockIdx.x];
  if (i == 0) out[n] = E;
}

__global__ __launch_bounds__(256) void k_scatter_r(const int* __restrict__ src_s,
                                                   const int* __restrict__ dst_s,
                                                   const int* __restrict__ src_v,
                                                   const int* __restrict__ dst_v,
                                                   const int* __restrict__ rowptr_s,
                                                   const int* __restrict__ rowptr_v,
                                                   int* __restrict__ cursor_s,
                                                   int* __restrict__ cursor_v,
                                                   unsigned short* __restrict__ srcp_s,
                                                   unsigned short* __restrict__ srcp_v) {
  int bid = blockIdx.x;
  int r = bid & 7;
  int i = (bid >> 3)*256 + threadIdx.x;
  if (i < EN_) {
    int d = dst_s[i];
    int lo = r*RNG_S;
    if (d >= lo && d < lo + RNG_S) {
      int pos = rowptr_s[d] + atomicAdd(&cursor_s[d], 1);
      srcp_s[pos] = (unsigned short)src_s[i];
    }
  } else if (i < EN_ + EV_) {
    int j = i - EN_;
    int d = dst_v[j];
    int lo = r*RNG_V;
    if (d >= lo && d < lo + RNG_V) {
      int pos = rowptr_v[d] + atomicAdd(&cursor_v[d], 1);
      srcp_v[pos] = (unsigned short)src_v[j];
    }
  }
}

// ---------- fused weight prep: W_ih transpose + 5x split ----------
__global__ __launch_bounds__(256) void k_prep(const float* W_ih, const float* Ws2,
                                              const float* Ws3, const float* W_attn,
                                              const float* Wv2, const float* Wv3,
                                              float* WTih,
                                              unsigned short* WS2hi, unsigned short* WS2lo,
                                              unsigned short* WS3hi, unsigned short* WS3lo,
                                              unsigned short* WAhi, unsigned short* WAlo,
                                              unsigned short* WV2hi, unsigned short* WV2lo,
                                              unsigned short* WV3hi, unsigned short* WV3lo) {
  int idx = blockIdx.x*256 + threadIdx.x;
  int task = blockIdx.y;
  if (task == 0) {
    if (idx < 128*384) {
      int k = idx / 384, j = idx - k*384;
      WTih[idx] = W_ih[(size_t)j*128 + k];
    }
  } else {
    if (idx >= 128*128) return;
    int j = idx >> 7, k = idx & 127;
    float v; unsigned short *hi, *lo;
    if (task == 1)      { v = Ws2[(size_t)k*128 + j];    hi = WS2hi; lo = WS2lo; }
    else if (task == 2) { v = Ws3[(size_t)k*128 + j];    hi = WS3hi; lo = WS3lo; }
    else if (task == 3) { v = W_attn[(size_t)j*256 + k]; hi = WAhi;  lo = WAlo;  }
    else if (task == 4) { v = Wv2[(size_t)k*128 + j];    hi = WV2hi; lo = WV2lo; }
    else                { v = Wv3[(size_t)k*128 + j];    hi = WV3hi; lo = WV3lo; }
    unsigned short h = bf16_rne(v);
    hi[idx] = h; lo[idx] = bf16_rne(v - bf16_tof(h));
  }
}

// ---------- static-path aggregate: masked 8-batches (no serial tail) ----------
__global__ __launch_bounds__(256) void k_aggregate_split(int nNodes, const int* __restrict__ rowptr,
    const unsigned short* __restrict__ srcp, const float* __restrict__ el, const float* __restrict__ er,
    const unsigned short* __restrict__ z, const float* __restrict__ bias,
    unsigned short* __restrict__ outHi, unsigned short* __restrict__ outLo) {
  int w = (blockIdx.x*256 + threadIdx.x) >> 6;
  int lane = threadIdx.x & 63;
  if (w >= nNodes) return;
  int beg = rowptr[w], end = rowptr[w+1];
  float erw = er[w];
  float a0 = 0.f, a1 = 0.f, wsum = 0.f;
  for (int i = beg; i < end; i += 8) {
    int sI[8]; float lv[8]; ushort2 q[8];
    #pragma unroll
    for (int u = 0; u < 8; ++u) {
      int idx = i + u; idx = (idx < end) ? idx : (end - 1);
      sI[u] = srcp[idx];
    }
    #pragma unroll
    for (int u = 0; u < 8; ++u) lv[u] = el[sI[u]];
    #pragma unroll
    for (int u = 0; u < 8; ++u) q[u] = *(const ushort2*)(z + (size_t)sI[u]*H_ + lane*2);
    #pragma unroll
    for (int u = 0; u < 8; ++u) {
      float wt = (i + u < end) ? __expf(lrelu02(lv[u] + erw)) : 0.f;
      a0 += wt*bf16_tof(q[u].x);
      a1 += wt*bf16_tof(q[u].y);
      wsum += wt;
    }
  }
  float inv = (end > beg) ? fast_rcp(wsum) : 0.f;
  float o0 = a0*inv + bias[lane*2];
  float o1 = a1*inv + bias[lane*2 + 1];
  unsigned short h0 = bf16_rne(o0), h1 = bf16_rne(o1);
  ushort2 hv; hv.x = h0; hv.y = h1;
  ushort2 lv2; lv2.x = bf16_rne(o0 - bf16_tof(h0)); lv2.y = bf16_rne(o1 - bf16_tof(h1));
  *(ushort2*)(outHi + (size_t)w*H_ + lane*2) = hv;
  *(ushort2*)(outLo + (size_t)w*H_ + lane*2) = lv2;
}

// ---------- MFMA split-bf16 GEMM: C/Cb[M,128] = (Ahi+Alo)@(Whi+Wlo), WT[col][k] ----------
__global__ __launch_bounds__(256) void k_mfma_gemm(
    const unsigned short* __restrict__ Ahi, const unsigned short* __restrict__ Alo,
    const unsigned short* __restrict__ WThi, const unsigned short* __restrict__ WTlo,
    float* __restrict__ C, unsigned short* __restrict__ Cb,
    const float* __restrict__ al, const float* __restrict__ ar,
    float* __restrict__ el, float* __restrict__ er) {
  __shared__ unsigned short lAhi[64*136];
  __shared__ unsigned short lAlo[64*136];
  __shared__ float redl[4][64];
  __shared__ float redr[4][64];
  int t = threadIdx.x;
  int row0 = blockIdx.x * 64;
  int wid = t >> 6, lane = t & 63;
  int g = lane >> 4, c = lane & 15;

  #pragma unroll
  for (int i = 0; i < 4; ++i) {
    int m = t + 256*i;
    int r = m >> 4;
    int kc = (m & 15) * 8;
    *(short8v*)(lAhi + r*136 + kc) = *(const short8v*)(Ahi + (size_t)(row0 + r)*H_ + kc);
    *(short8v*)(lAlo + r*136 + kc) = *(const short8v*)(Alo + (size_t)(row0 + r)*H_ + kc);
  }

  short8v bhi[2][4], blo[2][4];
  #pragma unroll
  for (int ct = 0; ct < 2; ++ct) {
    int col = wid*32 + ct*16 + c;
    #pragma unroll
    for (int kb = 0; kb < 4; ++kb) {
      size_t o = (size_t)col*H_ + kb*32 + g*8;
      bhi[ct][kb] = *(const short8v*)(WThi + o);
      blo[ct][kb] = *(const short8v*)(WTlo + o);
    }
  }

  floatx4 acc[4][2];
  #pragma unroll
  for (int rt = 0; rt < 4; ++rt)
    #pragma unroll
    for (int ct = 0; ct < 2; ++ct)
      acc[rt][ct] = (floatx4){0.f, 0.f, 0.f, 0.f};

  __syncthreads();

  #pragma unroll
  for (int kb = 0; kb < 4; ++kb) {
    short8v ahi[4], alo[4];
    #pragma unroll
    for (int rt = 0; rt < 4; ++rt) {
      int r = rt*16 + c;
      ahi[rt] = *(const short8v*)(lAhi + r*136 + kb*32 + g*8);
      alo[rt] = *(const short8v*)(lAlo + r*136 + kb*32 + g*8);
    }
    #pragma unroll
    for (int rt = 0; rt < 4; ++rt)
      #pragma unroll
      for (int ct = 0; ct < 2; ++ct) {
        acc[rt][ct] = __builtin_amdgcn_mfma_f32_16x16x32_bf16(ahi[rt], bhi[ct][kb], acc[rt][ct], 0, 0, 0);
        acc[rt][ct] = __builtin_amdgcn_mfma_f32_16x16x32_bf16(alo[rt], bhi[ct][kb], acc[rt][ct], 0, 0, 0);
        acc[rt][ct] = __builtin_amdgcn_mfma_f32_16x16x32_bf16(ahi[rt], blo[ct][kb], acc[rt][ct], 0, 0, 0);
      }
  }

  #pragma unroll
  for (int rt = 0; rt < 4; ++rt)
    #pragma unroll
    for (int i = 0; i < 4; ++i) {
      int row = row0 + rt*16 + g*4 + i;
      if (Cb) {
        unsigned short* cr = Cb + (size_t)row*H_ + wid*32;
        cr[c]      = bf16_rne(acc[rt][0][i]);
        cr[16 + c] = bf16_rne(acc[rt][1][i]);
      } else {
        float* cr = C + (size_t)row*H_ + wid*32;
        cr[c]      = acc[rt][0][i];
        cr[16 + c] = acc[rt][1][i];
      }
    }

  if (el) {
    float av0 = al[wid*32 + c], av1 = al[wid*32 + 16 + c];
    float rv0 = ar[wid*32 + c], rv1 = ar[wid*32 + 16 + c];
    #pragma unroll
    for (int rt = 0; rt < 4; ++rt)
      #pragma unroll
      for (int i = 0; i < 4; ++i) {
        float pl = acc[rt][0][i]*av0 + acc[rt][1][i]*av1;
        float pr = acc[rt][0][i]*rv0 + acc[rt][1][i]*rv1;
        pl += __shfl_xor(pl, 1, 64); pl += __shfl_xor(pl, 2, 64);
        pl += __shfl_xor(pl, 4, 64); pl += __shfl_xor(pl, 8, 64);
        pr += __shfl_xor(pr, 1, 64); pr += __shfl_xor(pr, 2, 64);
        pr += __shfl_xor(pr, 4, 64); pr += __shfl_xor(pr, 8, 64);
        if (c == 0) { redl[wid][rt*16 + g*4 + i] = pl; redr[wid][rt*16 + g*4 + i] = pr; }
      }
    __syncthreads();
    if (t < 64) {
      el[row0 + t] = redl[0][t] + redl[1][t] + redl[2][t] + redl[3][t];
      er[row0 + t] = redr[0][t] + redr[1][t] + redr[2][t] + redr[3][t];
    }
  }
}

// ---------- FUSED A1-MFMA + attention v2: LDS relay (no atomics) ----------
// Phase 1: MFMA computes A1 tile. Phase 2: tile stored f32 into the (reused)
// staging LDS. Phase 3: verbatim attn3 epilogue (thread = row x quarter,
// acc[10] in regs, 2 shuffles/step).
__global__ __launch_bounds__(256) void k_mfma_attn(
    const unsigned short* __restrict__ Ahi, const unsigned short* __restrict__ Alo,
    const unsigned short* __restrict__ WThi, const unsigned short* __restrict__ WTlo,
    const float* __restrict__ A2, const float* __restrict__ v_attn,
    const int* __restrict__ vnr_VNF, const int* __restrict__ net_VNF,
    float* __restrict__ pi) {
  __shared__ unsigned short lA[2][64*136];   // staging; reused as f32 A1 tile [64][132]
  __shared__ float a2s2[2][10][128];         // 2*A2 for the <=2 batches this block spans
  __shared__ float vv2s[128];                // 2*v
  int t = threadIdx.x;
  int row0 = blockIdx.x * 64;
  int wid = t >> 6, lane = t & 63;
  int g = lane >> 4, c = lane & 15;
  int b0 = row0 / NN_;
  int b1 = (row0 + 63) / NN_; if (b1 > B_-1) b1 = B_-1;

  unsigned short* lAhi = lA[0];
  unsigned short* lAlo = lA[1];
  #pragma unroll
  for (int i = 0; i < 4; ++i) {
    int m = t + 256*i;
    int r = m >> 4;
    int kc = (m & 15) * 8;
    *(short8v*)(lAhi + r*136 + kc) = *(const short8v*)(Ahi + (size_t)(row0 + r)*H_ + kc);
    *(short8v*)(lAlo + r*136 + kc) = *(const short8v*)(Alo + (size_t)(row0 + r)*H_ + kc);
  }
  // stage 2*A2 for both candidate batches (each slab is 10*128=1280 floats)
  for (int i = t; i < 2560; i += 256) {
    int w = (i >= 1280) ? 1 : 0;
    int rem = i - w*1280;
    int s = rem >> 7, k = rem & 127;
    int b = (w == 0) ? b0 : b1;
    a2s2[w][s][k] = 2.f*A2[((size_t)s*B_ + b)*H_ + k];
  }
  if (t < 128) vv2s[t] = 2.f*v_attn[t];

  short8v bhi[2][4], blo[2][4];
  #pragma unroll
  for (int ct = 0; ct < 2; ++ct) {
    int col = wid*32 + ct*16 + c;
    #pragma unroll
    for (int kb = 0; kb < 4; ++kb) {
      size_t o = (size_t)col*H_ + kb*32 + g*8;
      bhi[ct][kb] = *(const short8v*)(WThi + o);
      blo[ct][kb] = *(const short8v*)(WTlo + o);
    }
  }

  floatx4 acc[4][2];
  #pragma unroll
  for (int rt = 0; rt < 4; ++rt)
    #pragma unroll
    for (int ct = 0; ct < 2; ++ct)
      acc[rt][ct] = (floatx4){0.f, 0.f, 0.f, 0.f};

  __syncthreads();

  #pragma unroll
  for (int kb = 0; kb < 4; ++kb) {
    short8v ahi[4], alo[4];
    #pragma unroll
    for (int rt = 0; rt < 4; ++rt) {
      int r = rt*16 + c;
      ahi[rt] = *(const short8v*)(lAhi + r*136 + kb*32 + g*8);
      alo[rt] = *(const short8v*)(lAlo + r*136 + kb*32 + g*8);
    }
    #pragma unroll
    for (int rt = 0; rt < 4; ++rt)
      #pragma unroll
      for (int ct = 0; ct < 2; ++ct) {
        acc[rt][ct] = __builtin_amdgcn_mfma_f32_16x16x32_bf16(ahi[rt], bhi[ct][kb], acc[rt][ct], 0, 0, 0);
        acc[rt][ct] = __builtin_amdgcn_mfma_f32_16x16x32_bf16(alo[rt], bhi[ct][kb], acc[rt][ct], 0, 0, 0);
        acc[rt][ct] = __builtin_amdgcn_mfma_f32_16x16x32_bf16(ahi[rt], blo[ct][kb], acc[rt][ct], 0, 0, 0);
      }
  }

  __syncthreads();   // all waves done reading staging LDS

  // relay: write f32 A1 tile (stride 132 words; 2-way bank aliasing only)
  float* a1s = (float*)lA;
  #pragma unroll
  for (int rt = 0; rt < 4; ++rt)
    #pragma unroll
    for (int i = 0; i < 4; ++i) {
      int lrow = rt*16 + g*4 + i;
      a1s[lrow*132 + wid*32 + c]      = acc[rt][0][i];
      a1s[lrow*132 + wid*32 + 16 + c] = acc[rt][1][i];
    }
  __syncthreads();

  // attn3 epilogue: thread owns (row nl, quarter p)
  int nl = t >> 2, p = t & 3;
  int row = row0 + nl;
  int b = row / NN_, n = row - b*NN_;
  int w = (b != b0) ? 1 : 0;
  const float* arow = a1s + nl*132 + p*32;
  float4 a[8], w2[8];
  #pragma unroll
  for (int kk = 0; kk < 8; ++kk) {
    float4 av = *(const float4*)(arow + kk*4);
    a[kk] = make_float4(2.f*av.x, 2.f*av.y, 2.f*av.z, 2.f*av.w);
    w2[kk] = *(const float4*)(&vv2s[p*32 + kk*4]);
  }
  float vsum = 0.f;
  #pragma unroll
  for (int kk = 0; kk < 8; ++kk)
    vsum += (w2[kk].x + w2[kk].y) + (w2[kk].z + w2[kk].w);
  vsum *= 0.5f;
  float accs[10];
  #pragma unroll
  for (int s = 0; s < 10; ++s) {
    const float* a2r = &a2s2[w][s][p*32];
    float sum2 = 0.f;
    #pragma unroll
    for (int kk = 0; kk < 8; ++kk) {
      float4 cc = *(const float4*)(a2r + kk*4);
      sum2 = fmaf(w2[kk].x, fast_rcp(1.f + __expf(a[kk].x + cc.x)), sum2);
      sum2 = fmaf(w2[kk].y, fast_rcp(1.f + __expf(a[kk].y + cc.y)), sum2);
      sum2 = fmaf(w2[kk].z, fast_rcp(1.f + __expf(a[kk].z + cc.z)), sum2);
      sum2 = fmaf(w2[kk].w, fast_rcp(1.f + __expf(a[kk].w + cc.w)), sum2);
    }
    accs[s] = vsum - sum2;
  }
  #pragma unroll
  for (int s = 0; s < 10; ++s) {
    accs[s] += __shfl_xor(accs[s], 1, 64);
    accs[s] += __shfl_xor(accs[s], 2, 64);
  }
  if (p == 0) {
    #pragma unroll
    for (int s = 0; s < 10; ++s) {
      int vnf = vnr_VNF[b*NV_ + s];
      int m   = net_VNF[(size_t)row*T_ + vnf];
      pi[(size_t)b*(NV_*NN_) + (size_t)s*NN_ + n] = accs[s] + __logf((float)m);
    }
  }
}

// ---------- FUSED aggregate -> MFMA GEMM (vnr path only: 10 blocks, tiny) ----------
__global__ __launch_bounds__(256) void k_agg_mfma(
    const int* __restrict__ rowptr, const unsigned short* __restrict__ srcp,
    const float* __restrict__ el_in, const float* __restrict__ er_in,
    const unsigned short* __restrict__ z_in, const float* __restrict__ bias,
    const unsigned short* __restrict__ WThi, const unsigned short* __restrict__ WTlo,
    unsigned short* __restrict__ zb_out, float* __restrict__ Cf,
    const float* __restrict__ al, const float* __restrict__ ar,
    float* __restrict__ el_out, float* __restrict__ er_out) {
  __shared__ unsigned short lAhi[64*136];
  __shared__ unsigned short lAlo[64*136];
  __shared__ float redl[4][64];
  __shared__ float redr[4][64];
  int t = threadIdx.x;
  int row0 = blockIdx.x * 64;
  int wid = t >> 6, lane = t & 63;
  int g = lane >> 4, c = lane & 15;

  float b0 = bias[lane*2], b1 = bias[lane*2 + 1];

  for (int j = 0; j < 8; ++j) {
    int wA = row0 + wid*16 + 2*j;
    int wB = wA + 1;
    int begA = rowptr[wA], endA = rowptr[wA+1];
    int begB = rowptr[wB], endB = rowptr[wB+1];
    float erA = er_in[wA], erB = er_in[wB];
    float a0A = 0.f, a1A = 0.f, wsA = 0.f;
    float a0B = 0.f, a1B = 0.f, wsB = 0.f;
    int iA = begA, iB = begB;
    while (iA < endA || iB < endB) {
      int sA[8], sB[8];
      #pragma unroll
      for (int u = 0; u < 8; ++u) {
        sA[u] = (iA + u < endA) ? (int)srcp[iA + u] : 0;
        sB[u] = (iB + u < endB) ? (int)srcp[iB + u] : 0;
      }
      float lA[8], lB[8];
      #pragma unroll
      for (int u = 0; u < 8; ++u) { lA[u] = el_in[sA[u]]; lB[u] = el_in[sB[u]]; }
      ushort2 qA[8], qB[8];
      #pragma unroll
      for (int u = 0; u < 8; ++u) {
        qA[u] = *(const ushort2*)(z_in + (size_t)sA[u]*H_ + lane*2);
        qB[u] = *(const ushort2*)(z_in + (size_t)sB[u]*H_ + lane*2);
      }
      #pragma unroll
      for (int u = 0; u < 8; ++u) {
        float wtA = (iA + u < endA) ? __expf(lrelu02(lA[u] + erA)) : 0.f;
        float wtB = (iB + u < endB) ? __expf(lrelu02(lB[u] + erB)) : 0.f;
        a0A += wtA*bf16_tof(qA[u].x); a1A += wtA*bf16_tof(qA[u].y); wsA += wtA;
        a0B += wtB*bf16_tof(qB[u].x); a1B += wtB*bf16_tof(qB[u].y); wsB += wtB;
      }
      iA += 8; iB += 8;
    }
    float invA = (endA > begA) ? fast_rcp(wsA) : 0.f;
    float invB = (endB > begB) ? fast_rcp(wsB) : 0.f;
    float o0A = a0A*invA + b0, o1A = a1A*invA + b1;
    float o0B = a0B*invB + b0, o1B = a1B*invB + b1;
    int rA = wid*16 + 2*j;
    unsigned short hA0 = bf16_rne(o0A), hA1 = bf16_rne(o1A);
    unsigned short hB0 = bf16_rne(o0B), hB1 = bf16_rne(o1B);
    ushort2 hvA; hvA.x = hA0; hvA.y = hA1;
    ushort2 lvA; lvA.x = bf16_rne(o0A - bf16_tof(hA0)); lvA.y = bf16_rne(o1A - bf16_tof(hA1));
    ushort2 hvB; hvB.x = hB0; hvB.y = hB1;
    ushort2 lvB; lvB.x = bf16_rne(o0B - bf16_tof(hB0)); lvB.y = bf16_rne(o1B - bf16_tof(hB1));
    *(ushort2*)(lAhi + rA*136 + lane*2) = hvA;
    *(ushort2*)(lAlo + rA*136 + lane*2) = lvA;
    *(ushort2*)(lAhi + (rA+1)*136 + lane*2) = hvB;
    *(ushort2*)(lAlo + (rA+1)*136 + lane*2) = lvB;
  }

  short8v bhi[2][4], blo[2][4];
  #pragma unroll
  for (int ct = 0; ct < 2; ++ct) {
    int col = wid*32 + ct*16 + c;
    #pragma unroll
    for (int kb = 0; kb < 4; ++kb) {
      size_t o = (size_t)col*H_ + kb*32 + g*8;
      bhi[ct][kb] = *(const short8v*)(WThi + o);
      blo[ct][kb] = *(const short8v*)(WTlo + o);
    }
  }

  floatx4 acc[4][2];
  #pragma unroll
  for (int rt = 0; rt < 4; ++rt)
    #pragma unroll
    for (int ct = 0; ct < 2; ++ct)
      acc[rt][ct] = (floatx4){0.f, 0.f, 0.f, 0.f};

  __syncthreads();

  #pragma unroll
  for (int kb = 0; kb < 4; ++kb) {
    short8v ahi[4], alo[4];
    #pragma unroll
    for (int rt = 0; rt < 4; ++rt) {
      int r = rt*16 + c;
      ahi[rt] = *(const short8v*)(lAhi + r*136 + kb*32 + g*8);
      alo[rt] = *(const short8v*)(lAlo + r*136 + kb*32 + g*8);
    }
    #pragma unroll
    for (int rt = 0; rt < 4; ++rt)
      #pragma unroll
      for (int ct = 0; ct < 2; ++ct) {
        acc[rt][ct] = __builtin_amdgcn_mfma_f32_16x16x32_bf16(ahi[rt], bhi[ct][kb], acc[rt][ct], 0, 0, 0);
        acc[rt][ct] = __builtin_amdgcn_mfma_f32_16x16x32_bf16(alo[rt], bhi[ct][kb], acc[rt][ct], 0, 0, 0);
        acc[rt][ct] = __builtin_amdgcn_mfma_f32_16x16x32_bf16(ahi[rt], blo[ct][kb], acc[rt][ct], 0, 0, 0);
      }
  }

  #pragma unroll
  for (int rt = 0; rt < 4; ++rt)
    #pragma unroll
    for (int i = 0; i < 4; ++i) {
      int row = row0 + rt*16 + g*4 + i;
      if (zb_out) {
        unsigned short* cr = zb_out + (size_t)row*H_ + wid*32;
        cr[c]      = bf16_rne(acc[rt][0][i]);
        cr[16 + c] = bf16_rne(acc[rt][1][i]);
      } else {
        float* cr = Cf + (size_t)row*H_ + wid*32;
        cr[c]      = acc[rt][0][i];
        cr[16 + c] = acc[rt][1][i];
      }
    }

  if (el_out) {
    float av0 = al[wid*32 + c], av1 = al[wid*32 + 16 + c];
    float rv0 = ar[wid*32 + c], rv1 = ar[wid*32 + 16 + c];
    #pragma unroll
    for (int rt = 0; rt < 4; ++rt)
      #pragma unroll
      for (int i = 0; i < 4; ++i) {
        float pl = acc[rt][0][i]*av0 + acc[rt][1][i]*av1;
        float pr = acc[rt][0][i]*rv0 + acc[rt][1][i]*rv1;
        pl += __shfl_xor(pl, 1, 64); pl += __shfl_xor(pl, 2, 64);
        pl += __shfl_xor(pl, 4, 64); pl += __shfl_xor(pl, 8, 64);
        pr += __shfl_xor(pr, 1, 64); pr += __shfl_xor(pr, 2, 64);
        pr += __shfl_xor(pr, 4, 64); pr += __shfl_xor(pr, 8, 64);
        if (c == 0) { redl[wid][rt*16 + g*4 + i] = pl; redr[wid][rt*16 + g*4 + i] = pr; }
      }
    __syncthreads();
    if (t < 64) {
      el_out[row0 + t] = redl[0][t] + redl[1][t] + redl[2][t] + redl[3][t];
      er_out[row0 + t] = redr[0][t] + redr[1][t] + redr[2][t] + redr[3][t];
    }
  }
}

// ---------- plain aggregate: bf16 z in, f32 out (vnr layer 3) ----------
__global__ __launch_bounds__(256) void k_aggregate_f(int nNodes, const int* __restrict__ rowptr,
    const unsigned short* __restrict__ srcp, const float* __restrict__ el,
    const float* __restrict__ er, const unsigned short* __restrict__ z,
    const float* __restrict__ bias, float* __restrict__ out) {
  int w = (blockIdx.x*256 + threadIdx.x) >> 6;
  int lane = threadIdx.x & 63;
  if (w >= nNodes) return;
  int beg = rowptr[w], end = rowptr[w+1];
  float erw = er[w];
  float a0 = 0.f, a1 = 0.f, wsum = 0.f;
  for (int i = beg; i < end; ++i) {
    int sI = srcp[i];
    float wt = __expf(lrelu02(el[sI] + erw));
    ushort2 q = *(const ushort2*)(z + (size_t)sI*H_ + lane*2);
    a0 += wt*bf16_tof(q.x); a1 += wt*bf16_tof(q.y); wsum += wt;
  }
  float inv = (end > beg) ? fast_rcp(wsum) : 0.f;
  float2 o;
  o.x = a0*inv + bias[lane*2];
  o.y = a1*inv + bias[lane*2 + 1];
  *(float2*)(out + (size_t)w*H_ + lane*2) = o;
}

// ---------- generic f32 GEMM (layer-1 static, layer-1 vnr, GI) ----------
__global__ __launch_bounds__(256) void k_gemm(const float* A, int M, int K, int N,
                                              const float* W, const float* bias,
                                              float* C, unsigned short* Cb,
                                              const float* al, const float* ar,
                                              float* el, float* er) {
  __shared__ float Ws_[64*128];
  __shared__ float As_[16*128];
  __shared__ float redl[16][17];
  __shared__ float redr[16][17];
  int t = threadIdx.x;
  int j0 = blockIdx.y * 128;
  int row0 = blockIdx.x * 16;
  for (int l = t; l < 16*K; l += 256) {
    int r = l / K, k = l - r*K;
    int row = row0 + r;
    As_[r*K + k] = (row < M) ? A[(size_t)row*K + k] : 0.f;
  }
  int jg = t & 15, r = t >> 4;
  float acc[8];
  #pragma unroll
  for (int q = 0; q < 8; ++q) acc[q] = 0.f;
  for (int kc = 0; kc < K; kc += 64) {
    int kl = min(64, K - kc);
    __syncthreads();
    for (int l = t; l < (kl << 7); l += 256) {
      int k = l >> 7, j = l & 127;
      int jj = j0 + j;
      Ws_[l] = (jj < N) ? W[(size_t)(kc + k)*N + jj] : 0.f;
    }
    __syncthreads();
    for (int k = 0; k < kl; ++k) {
      float a = As_[r*K + kc + k];
      const float* wr = &Ws_[(k << 7) + jg*8];
      #pragma unroll
      for (int q = 0; q < 8; ++q) acc[q] += a * wr[q];
    }
  }
  int row = row0 + r;
  if (row < M) {
    if (Cb) {
      unsigned short* crow = Cb + (size_t)row*N + j0 + jg*8;
      #pragma unroll
      for (int q = 0; q < 8; ++q) {
        int j = j0 + jg*8 + q;
        if (j < N) crow[q] = bf16_rne(acc[q] + (bias ? bias[j] : 0.f));
      }
    } else {
      float* crow = C + (size_t)row*N + j0 + jg*8;
      #pragma unroll
      for (int q = 0; q < 8; ++q) {
        int j = j0 + jg*8 + q;
        if (j < N) crow[q] = acc[q] + (bias ? bias[j] : 0.f);
      }
    }
  }
  if (el) {
    float pl = 0.f, pr = 0.f;
    #pragma unroll
    for (int q = 0; q < 8; ++q) {
      int j = jg*8 + q;
      pl += acc[q]*al[j];
      pr += acc[q]*ar[j];
    }
    redl[r][jg] = pl; redr[r][jg] = pr;
    __syncthreads();
    if (t < 16) {
      float sl = 0.f, sr = 0.f;
      for (int q = 0; q < 16; ++q) { sl += redl[t][q]; sr += redr[t][q]; }
      int row2 = row0 + t;
      if (row2 < M) { el[row2] = sl; er[row2] = sr; }
    }
  }
}

// ---------- GRU decoder: weights register-resident, LDS-broadcast h ----------
__global__ __launch_bounds__(512) void k_decoder(const float* __restrict__ GI,
                                                 const float* __restrict__ W_hh,
                                                 const float* __restrict__ b_hh,
                                                 const float* __restrict__ W_attn,
                                                 const float* __restrict__ h0,
                                                 float* __restrict__ A2) {
  int b = blockIdx.x;
  __shared__ float h[128];
  __shared__ float gh[384];
  int t = threadIdx.x;
  const float4* wsrc = (t < 384)
      ? (const float4*)(W_hh + (size_t)t*128)
      : (const float4*)(W_attn + (size_t)(t-384)*256 + 128);
  float4 wreg[32];
  #pragma unroll
  for (int kk = 0; kk < 32; ++kk) wreg[kk] = wsrc[kk];
  float bh = (t < 384) ? b_hh[t] : 0.f;
  if (t < 128) h[t] = h0[t];
  __syncthreads();
  for (int s = 0; s < 10; ++s) {
    const float4* h4 = (const float4*)h;
    if (t < 384) {
      float a0 = 0.f, a1 = 0.f, a2 = 0.f, a3 = 0.f;
      #pragma unroll
      for (int kk = 0; kk < 32; kk += 4) {
        a0 += dot4(wreg[kk+0], h4[kk+0]);
        a1 += dot4(wreg[kk+1], h4[kk+1]);
        a2 += dot4(wreg[kk+2], h4[kk+2]);
        a3 += dot4(wreg[kk+3], h4[kk+3]);
      }
      gh[t] = (a0 + a1) + (a2 + a3) + bh;
    }
    __syncthreads();
    if (t < 128) {
      const float* gi = GI + (size_t)(b*NV_ + s)*384;
      float rr = fast_sigmoid(gi[t]       + gh[t]);
      float zz = fast_sigmoid(gi[128 + t] + gh[128 + t]);
      float nn = fast_tanh   (gi[256 + t] + rr*gh[256 + t]);
      h[t] = (1.f - zz)*nn + zz*h[t];
    }
    __syncthreads();
    if (t >= 384) {
      float a0 = 0.f, a1 = 0.f, a2 = 0.f, a3 = 0.f;
      #pragma unroll
      for (int kk = 0; kk < 32; kk += 4) {
        a0 += dot4(wreg[kk+0], h4[kk+0]);
        a1 += dot4(wreg[kk+1], h4[kk+1]);
        a2 += dot4(wreg[kk+2], h4[kk+2]);
        a3 += dot4(wreg[kk+3], h4[kk+3]);
      }
      A2[((size_t)s*B_ + b)*128 + (t - 384)] = (a0 + a1) + (a2 + a3);
    }
  }
}

// ---------- value head ----------
__global__ __launch_bounds__(128) void k_y2s(const unsigned short* hi, const unsigned short* lo,
                                             float* y2) {
  int b = blockIdx.x, slice = blockIdx.y, h = threadIdx.x;
  int n0 = slice*125, n1 = n0 + 125;
  float s = 0.f;
  for (int n = n0; n < n1; ++n) {
    size_t idx = ((size_t)b*NN_ + n)*H_ + h;
    s += bf16_tof(hi[idx]) + bf16_tof(lo[idx]);
  }
  atomicAdd(&y2[b*H_ + h], s);
}

__global__ __launch_bounds__(128) void k_value(const float* __restrict__ Hv,
                                               const float* __restrict__ nmask,
                                               const float* __restrict__ y2,
                                               const float* __restrict__ W_out,
                                               const float* __restrict__ b_out,
                                               float* __restrict__ val) {
  __shared__ float y1s[128];
  int b = blockIdx.x, t = threadIdx.x;
  float s = 0.f, d = 0.f;
  #pragma unroll
  for (int i = 0; i < NV_; ++i) {
    float m = nmask[b*NV_ + i];
    s += Hv[(size_t)(b*NV_ + i)*H_ + t]*m;
    d += m;
  }
  y1s[t] = s/d;
  __syncthreads();
  if (t < 64) {
    const float* w = W_out + (size_t)t*256;
    float acc = b_out[t];
    for (int h = 0; h < H_; ++h)
      acc += y1s[h]*w[h] + (y2[b*H_ + h]*(1.f/1000.f))*w[128 + h];
    val[b*O_ + t] = acc;
  }
}

extern "C" void kernel_launch(void* const* d_in, const int* in_sizes, int n_in,
                              void* d_out, int out_size, void* d_ws, size_t ws_size,
                              hipStream_t stream) {
  (void)in_sizes; (void)n_in; (void)out_size; (void)ws_size;
  const float* static_feat = (const float*)d_in[0];
  const float* vnr_feat    = (const float*)d_in[1];
  const float* nmask       = (const float*)d_in[2];
  const float* Ws1 = (const float*)d_in[3];  const float* als1 = (const float*)d_in[4];
  const float* ars1 = (const float*)d_in[5]; const float* bs1 = (const float*)d_in[6];
  const float* Ws2 = (const float*)d_in[7];  const float* als2 = (const float*)d_in[8];
  const float* ars2 = (const float*)d_in[9]; const float* bs2 = (const float*)d_in[10];
  const float* Ws3 = (const float*)d_in[11]; const float* als3 = (const float*)d_in[12];
  const float* ars3 = (const float*)d_in[13]; const float* bs3 = (const float*)d_in[14];
  const float* Wv1 = (const float*)d_in[15]; const float* alv1 = (const float*)d_in[16];
  const float* arv1 = (const float*)d_in[17]; const float* bv1 = (const float*)d_in[18];
  const float* Wv2 = (const float*)d_in[19]; const float* alv2 = (const float*)d_in[20];
  const float* arv2 = (const float*)d_in[21]; const float* bv2 = (const float*)d_in[22];
  const float* Wv3 = (const float*)d_in[23]; const float* alv3 = (const float*)d_in[24];
  const float* arv3 = (const float*)d_in[25]; const float* bv3 = (const float*)d_in[26];
  const float* W_attn = (const float*)d_in[27];
  const float* v_attn = (const float*)d_in[28];
  const float* W_ih = (const float*)d_in[29];
  const float* W_hh = (const float*)d_in[30];
  const float* b_ih = (const float*)d_in[31];
  const float* b_hh = (const float*)d_in[32];
  const float* h0   = (const float*)d_in[33];
  const float* W_out = (const float*)d_in[34];
  const float* b_out = (const float*)d_in[35];
  const int* src_s = (const int*)d_in[36];
  const int* dst_s = (const int*)d_in[37];
  const int* src_v = (const int*)d_in[38];
  const int* dst_v = (const int*)d_in[39];
  const int* vnr_VNF = (const int*)d_in[40];
  const int* net_VNF = (const int*)d_in[41];

  char* ws = (char*)d_ws;
  size_t off = 0;
  auto alloc = [&](size_t bytes) -> char* {
    off = (off + 255) & ~(size_t)255;
    char* p = ws + off;
    off += bytes;
    return p;
  };
  unsigned short* Zb0 = (unsigned short*)alloc((size_t)NS_*H_*2);   // bf16 z
  unsigned short* HsHi = (unsigned short*)alloc((size_t)NS_*H_*2);
  unsigned short* HsLo = (unsigned short*)alloc((size_t)NS_*H_*2);
  unsigned short* Zbv0 = (unsigned short*)alloc((size_t)NVT_*H_*2);
  unsigned short* Zbv1 = (unsigned short*)alloc((size_t)NVT_*H_*2);
  float* Hv   = (float*)alloc((size_t)NVT_*H_*4);
  float* el_s = (float*)alloc((size_t)NS_*4);
  float* er_s = (float*)alloc((size_t)NS_*4);
  float* elv_a = (float*)alloc((size_t)NVT_*4);
  float* erv_a = (float*)alloc((size_t)NVT_*4);
  float* elv_b = (float*)alloc((size_t)NVT_*4);
  float* erv_b = (float*)alloc((size_t)NVT_*4);
  size_t zcount = (size_t)NS_ + NS_ + NVT_ + NVT_ + B_*H_;
  char* zb = alloc(zcount*4);
  int*   counts_s = (int*)zb;
  int*   cursor_s = counts_s + NS_;
  int*   counts_v = cursor_s + NS_;
  int*   cursor_v = counts_v + NVT_;
  float* y2buf    = (float*)(cursor_v + NVT_);
  int* rowptr_s = (int*)alloc((size_t)(NS_+1)*4);
  int* rowptr_v = (int*)alloc((size_t)(NVT_+1)*4);
  int* bsum     = (int*)alloc((size_t)256*4);
  unsigned short* srcp_s = (unsigned short*)alloc((size_t)(EN_+8)*2);
  unsigned short* srcp_v = (unsigned short*)alloc((size_t)(EV_+8)*2);
  unsigned short* WS2hi = (unsigned short*)alloc((size_t)H_*H_*2);
  unsigned short* WS2lo = (unsigned short*)alloc((size_t)H_*H_*2);
  unsigned short* WS3hi = (unsigned short*)alloc((size_t)H_*H_*2);
  unsigned short* WS3lo = (unsigned short*)alloc((size_t)H_*H_*2);
  unsigned short* WAhi  = (unsigned short*)alloc((size_t)H_*H_*2);
  unsigned short* WAlo  = (unsigned short*)alloc((size_t)H_*H_*2);
  unsigned short* WV2hi = (unsigned short*)alloc((size_t)H_*H_*2);
  unsigned short* WV2lo = (unsigned short*)alloc((size_t)H_*H_*2);
  unsigned short* WV3hi = (unsigned short*)alloc((size_t)H_*H_*2);
  unsigned short* WV3lo = (unsigned short*)alloc((size_t)H_*H_*2);
  float* WTih   = (float*)alloc((size_t)H_*384*4);
  float* GI     = (float*)alloc((size_t)NVT_*384*4);
  float* A2     = (float*)alloc((size_t)NV_*B_*H_*4);

  float* pi  = (float*)d_out;
  float* val = pi + (size_t)B_*NV_*NN_;

  hipMemsetAsync(zb, 0, zcount*4, stream);

  k_prep<<<dim3(192, 6), 256, 0, stream>>>(W_ih, Ws2, Ws3, W_attn, Wv2, Wv3, WTih,
                                           WS2hi, WS2lo, WS3hi, WS3lo, WAhi, WAlo,
                                           WV2hi, WV2lo, WV3hi, WV3lo);

  // CSR build: XCD-ranged count + scatter
  int edgeChunks = (EN_ + EV_ + 255)/256;
  k_count_r<<<edgeChunks*8, 256, 0, stream>>>(dst_s, dst_v, counts_s, counts_v);
  k_scan_local<<<250, 256, 0, stream>>>(counts_s, NS_, rowptr_s, bsum);
  k_scan_small<<<2, 1024, 0, stream>>>(bsum, 250, counts_v, rowptr_v, NVT_);
  k_scan_add<<<250, 256, 0, stream>>>(rowptr_s, bsum, NS_, EN_);
  k_scatter_r<<<edgeChunks*8, 256, 0, stream>>>(src_s, dst_s, src_v, dst_v,
                                                rowptr_s, rowptr_v, cursor_s, cursor_v,
                                                srcp_s, srcp_v);

  int aggS = (NS_ + 3)/4;

  // ---- static GAT stack ----
  k_gemm<<<dim3(NS_/16, 1), 256, 0, stream>>>(static_feat, NS_, FS_, H_, Ws1, nullptr,
                                              nullptr, Zb0, als1, ars1, el_s, er_s);
  k_aggregate_split<<<aggS, 256, 0, stream>>>(NS_, rowptr_s, srcp_s, el_s, er_s, Zb0, bs1, HsHi, HsLo);
  k_mfma_gemm<<<NS_/64, 256, 0, stream>>>(HsHi, HsLo, WS2hi, WS2lo, nullptr, Zb0, als2, ars2, el_s, er_s);
  k_aggregate_split<<<aggS, 256, 0, stream>>>(NS_, rowptr_s, srcp_s, el_s, er_s, Zb0, bs2, HsHi, HsLo);
  k_mfma_gemm<<<NS_/64, 256, 0, stream>>>(HsHi, HsLo, WS3hi, WS3lo, nullptr, Zb0, als3, ars3, el_s, er_s);
  k_aggregate_split<<<aggS, 256, 0, stream>>>(NS_, rowptr_s, srcp_s, el_s, er_s, Zb0, bs3, HsHi, HsLo);
  k_y2s<<<dim3(B_, 8), 128, 0, stream>>>(HsHi, HsLo, y2buf);

  // ---- vnr GAT stack (tiny: fused agg+GEMM, 10 blocks) ----
  k_gemm<<<dim3(NVT_/16, 1), 256, 0, stream>>>(vnr_feat, NVT_, FV_, H_, Wv1, nullptr,
                                               nullptr, Zbv0, alv1, arv1, elv_a, erv_a);
  k_agg_mfma<<<NVT_/64, 256, 0, stream>>>(rowptr_v, srcp_v, elv_a, erv_a, Zbv0, bv1,
                                          WV2hi, WV2lo, Zbv1, nullptr,
                                          alv2, arv2, elv_b, erv_b);
  k_agg_mfma<<<NVT_/64, 256, 0, stream>>>(rowptr_v, srcp_v, elv_b, erv_b, Zbv1, bv2,
                                          WV3hi, WV3lo, Zbv0, nullptr,
                                          alv3, arv3, elv_a, erv_a);
  k_aggregate_f<<<(NVT_ + 3)/4, 256, 0, stream>>>(NVT_, rowptr_v, srcp_v, elv_a, erv_a,
                                                  Zbv0, bv3, Hv);

  // ---- decoder ----
  k_gemm<<<dim3(NVT_/16, 3), 256, 0, stream>>>(Hv, NVT_, H_, 384, WTih, b_ih, GI, nullptr,
                                               nullptr, nullptr, nullptr, nullptr);
  k_decoder<<<B_, 512, 0, stream>>>(GI, W_hh, b_hh, W_attn, h0, A2);
  // fused A1-MFMA + attention (LDS relay; no Z round trip, no atomics)
  k_mfma_attn<<<NS_/64, 256, 0, stream>>>(HsHi, HsLo, WAhi, WAlo, A2, v_attn,
                                          vnr_VNF, net_VNF, pi);

  // ---- value head ----
  k_value<<<B_, 128, 0, stream>>>(Hv, nmask, y2buf, W_out, b_out, val);
}

// Round 15
// 387.987 us; speedup vs baseline: 1.6916x; 1.0428x over previous
//
#include <hip/hip_runtime.h>
#include <hip/hip_bf16.h>
#include <math.h>

#define B_   64
#define NN_  1000
#define NV_  10
#define H_   128
#define FS_  8
#define FV_  6
#define T_   8
#define O_   64
#define EN_  512000
#define EV_  2560
#define NS_  (B_*NN_)   /* 64000 */
#define NVT_ (B_*NV_)   /* 640 */
#define RNG_S (NS_/8)   /* 8000 dst nodes per XCD range */
#define RNG_V (NVT_/8)  /* 80 */

typedef __attribute__((ext_vector_type(8))) short short8v;   // 8 bf16
typedef __attribute__((ext_vector_type(4))) float floatx4;

__device__ __forceinline__ float fast_rcp(float x) { return __builtin_amdgcn_rcpf(x); }
__device__ __forceinline__ float fast_tanh(float x) {
  return 1.f - 2.f*fast_rcp(1.f + __expf(2.f*x));
}
__device__ __forceinline__ float fast_sigmoid(float x) {
  return fast_rcp(1.f + __expf(-x));
}
__device__ __forceinline__ unsigned short bf16_rne(float x) {
  unsigned u = __float_as_uint(x);
  return (unsigned short)((u + 0x7FFFu + ((u >> 16) & 1u)) >> 16);
}
__device__ __forceinline__ float bf16_tof(unsigned short b) {
  return __uint_as_float(((unsigned)b) << 16);
}
__device__ __forceinline__ float dot4(float4 a, float4 b) {
  return a.x*b.x + a.y*b.y + a.z*b.z + a.w*b.w;
}
__device__ __forceinline__ float lrelu02(float e) {
  return (e > 0.f) ? e : 0.2f*e;
}

// ---------- CSR build: XCD-ranged count (atomics stay in one XCD's L2) ----------
__global__ __launch_bounds__(256) void k_count_r(const int* __restrict__ dst_s,
                                                 const int* __restrict__ dst_v,
                                                 int* __restrict__ counts_s,
                                                 int* __restrict__ counts_v) {
  int bid = blockIdx.x;
  int r = bid & 7;
  int i = (bid >> 3)*256 + threadIdx.x;
  if (i < EN_) {
    int d = dst_s[i];
    int lo = r*RNG_S;
    if (d >= lo && d < lo + RNG_S) atomicAdd(&counts_s[d], 1);
  } else if (i < EN_ + EV_) {
    int d = dst_v[i - EN_];
    int lo = r*RNG_V;
    if (d >= lo && d < lo + RNG_V) atomicAdd(&counts_v[d], 1);
  }
}

__global__ __launch_bounds__(256) void k_scan_local(const int* cnt, int n, int* out, int* bsum) {
  __shared__ int s[256];
  int t = threadIdx.x; int i = blockIdx.x*256 + t;
  int v = (i < n) ? cnt[i] : 0;
  s[t] = v; __syncthreads();
  #pragma unroll
  for (int o = 1; o < 256; o <<= 1) {
    int u = (t >= o) ? s[t-o] : 0; __syncthreads();
    s[t] += u; __syncthreads();
  }
  if (i < n) out[i] = s[t] - v;
  if (t == 255) bsum[blockIdx.x] = s[255];
}

__global__ __launch_bounds__(1024) void k_scan_small(int* bsum, int nb,
                                                     const int* cntv, int* rowptr_v, int nv) {
  __shared__ int sums[1024];
  int t = threadIdx.x;
  if (blockIdx.x == 0) {
    int v = (t < nb) ? bsum[t] : 0;
    sums[t] = v; __syncthreads();
    for (int o = 1; o < 1024; o <<= 1) {
      int u = (t >= o) ? sums[t-o] : 0; __syncthreads();
      sums[t] += u; __syncthreads();
    }
    if (t < nb) bsum[t] = sums[t] - v;
  } else {
    int v = (t < nv) ? cntv[t] : 0;
    sums[t] = v; __syncthreads();
    for (int o = 1; o < 1024; o <<= 1) {
      int u = (t >= o) ? sums[t-o] : 0; __syncthreads();
      sums[t] += u; __syncthreads();
    }
    if (t < nv) rowptr_v[t] = sums[t] - v;
    if (t == nv-1) rowptr_v[nv] = sums[t];
  }
}

__global__ __launch_bounds__(256) void k_scan_add(int* out, const int* bsum, int n, int E) {
  int i = blockIdx.x*256 + threadIdx.x;
  if (i < n) out[i] += bsum[blockIdx.x];
  if (i == 0) out[n] = E;
}

__global__ __launch_bounds__(256) void k_scatter_r(const int* __restrict__ src_s,
                                                   const int* __restrict__ dst_s,
                                                   const int* __restrict__ src_v,
                                                   const int* __restrict__ dst_v,
                                                   const int* __restrict__ rowptr_s,
                                                   const int* __restrict__ rowptr_v,
                                                   int* __restrict__ cursor_s,
                                                   int* __restrict__ cursor_v,
                                                   unsigned short* __restrict__ srcp_s,
                                                   unsigned short* __restrict__ srcp_v) {
  int bid = blockIdx.x;
  int r = bid & 7;
  int i = (bid >> 3)*256 + threadIdx.x;
  if (i < EN_) {
    int d = dst_s[i];
    int lo = r*RNG_S;
    if (d >= lo && d < lo + RNG_S) {
      int pos = rowptr_s[d] + atomicAdd(&cursor_s[d], 1);
      srcp_s[pos] = (unsigned short)src_s[i];
    }
  } else if (i < EN_ + EV_) {
    int j = i - EN_;
    int d = dst_v[j];
    int lo = r*RNG_V;
    if (d >= lo && d < lo + RNG_V) {
      int pos = rowptr_v[d] + atomicAdd(&cursor_v[d], 1);
      srcp_v[pos] = (unsigned short)src_v[j];
    }
  }
}

// ---------- fused weight prep: W_ih transpose + 5x split ----------
__global__ __launch_bounds__(256) void k_prep(const float* W_ih, const float* Ws2,
                                              const float* Ws3, const float* W_attn,
                                              const float* Wv2, const float* Wv3,
                                              float* WTih,
                                              unsigned short* WS2hi, unsigned short* WS2lo,
                                              unsigned short* WS3hi, unsigned short* WS3lo,
                                              unsigned short* WAhi, unsigned short* WAlo,
                                              unsigned short* WV2hi, unsigned short* WV2lo,
                                              unsigned short* WV3hi, unsigned short* WV3lo) {
  int idx = blockIdx.x*256 + threadIdx.x;
  int task = blockIdx.y;
  if (task == 0) {
    if (idx < 128*384) {
      int k = idx / 384, j = idx - k*384;
      WTih[idx] = W_ih[(size_t)j*128 + k];
    }
  } else {
    if (idx >= 128*128) return;
    int j = idx >> 7, k = idx & 127;
    float v; unsigned short *hi, *lo;
    if (task == 1)      { v = Ws2[(size_t)k*128 + j];    hi = WS2hi; lo = WS2lo; }
    else if (task == 2) { v = Ws3[(size_t)k*128 + j];    hi = WS3hi; lo = WS3lo; }
    else if (task == 3) { v = W_attn[(size_t)j*256 + k]; hi = WAhi;  lo = WAlo;  }
    else if (task == 4) { v = Wv2[(size_t)k*128 + j];    hi = WV2hi; lo = WV2lo; }
    else                { v = Wv3[(size_t)k*128 + j];    hi = WV3hi; lo = WV3lo; }
    unsigned short h = bf16_rne(v);
    hi[idx] = h; lo[idx] = bf16_rne(v - bf16_tof(h));
  }
}

// ---------- static-path aggregate: 2 nodes/wave (32 lanes each), masked 8-batches ----------
// Doubles independent gather chains in flight per wave; lane handles 4 features
// (ushort4). Halves wave count at equal total VALU.
__global__ __launch_bounds__(256) void k_aggregate_split(int nNodes, const int* __restrict__ rowptr,
    const unsigned short* __restrict__ srcp, const float* __restrict__ el, const float* __restrict__ er,
    const unsigned short* __restrict__ z, const float* __restrict__ bias,
    unsigned short* __restrict__ outHi, unsigned short* __restrict__ outLo) {
  int wv = (blockIdx.x*256 + threadIdx.x) >> 6;
  int lane = threadIdx.x & 63;
  int half = lane >> 5, l32 = lane & 31;
  int w = wv*2 + half;
  if (w >= nNodes) return;
  int beg = rowptr[w], end = rowptr[w+1];
  float erw = er[w];
  float4 bv = *(const float4*)(bias + l32*4);
  float a0 = 0.f, a1 = 0.f, a2 = 0.f, a3 = 0.f, wsum = 0.f;
  for (int i = beg; i < end; i += 8) {
    int sI[8]; float lv[8]; ushort4 q[8];
    #pragma unroll
    for (int u = 0; u < 8; ++u) {
      int idx = i + u; idx = (idx < end) ? idx : (end - 1);
      sI[u] = srcp[idx];
    }
    #pragma unroll
    for (int u = 0; u < 8; ++u) lv[u] = el[sI[u]];
    #pragma unroll
    for (int u = 0; u < 8; ++u) q[u] = *(const ushort4*)(z + (size_t)sI[u]*H_ + l32*4);
    #pragma unroll
    for (int u = 0; u < 8; ++u) {
      float wt = (i + u < end) ? __expf(lrelu02(lv[u] + erw)) : 0.f;
      a0 += wt*bf16_tof(q[u].x);
      a1 += wt*bf16_tof(q[u].y);
      a2 += wt*bf16_tof(q[u].z);
      a3 += wt*bf16_tof(q[u].w);
      wsum += wt;
    }
  }
  float inv = (end > beg) ? fast_rcp(wsum) : 0.f;
  float o0 = a0*inv + bv.x;
  float o1 = a1*inv + bv.y;
  float o2 = a2*inv + bv.z;
  float o3 = a3*inv + bv.w;
  unsigned short h0 = bf16_rne(o0), h1 = bf16_rne(o1), h2 = bf16_rne(o2), h3 = bf16_rne(o3);
  ushort4 hv; hv.x = h0; hv.y = h1; hv.z = h2; hv.w = h3;
  ushort4 lv4;
  lv4.x = bf16_rne(o0 - bf16_tof(h0));
  lv4.y = bf16_rne(o1 - bf16_tof(h1));
  lv4.z = bf16_rne(o2 - bf16_tof(h2));
  lv4.w = bf16_rne(o3 - bf16_tof(h3));
  *(ushort4*)(outHi + (size_t)w*H_ + l32*4) = hv;
  *(ushort4*)(outLo + (size_t)w*H_ + l32*4) = lv4;
}

// ---------- MFMA split-bf16 GEMM: C/Cb[M,128] = (Ahi+Alo)@(Whi+Wlo), WT[col][k] ----------
__global__ __launch_bounds__(256) void k_mfma_gemm(
    const unsigned short* __restrict__ Ahi, const unsigned short* __restrict__ Alo,
    const unsigned short* __restrict__ WThi, const unsigned short* __restrict__ WTlo,
    float* __restrict__ C, unsigned short* __restrict__ Cb,
    const float* __restrict__ al, const float* __restrict__ ar,
    float* __restrict__ el, float* __restrict__ er) {
  __shared__ unsigned short lAhi[64*136];
  __shared__ unsigned short lAlo[64*136];
  __shared__ float redl[4][64];
  __shared__ float redr[4][64];
  int t = threadIdx.x;
  int row0 = blockIdx.x * 64;
  int wid = t >> 6, lane = t & 63;
  int g = lane >> 4, c = lane & 15;

  #pragma unroll
  for (int i = 0; i < 4; ++i) {
    int m = t + 256*i;
    int r = m >> 4;
    int kc = (m & 15) * 8;
    *(short8v*)(lAhi + r*136 + kc) = *(const short8v*)(Ahi + (size_t)(row0 + r)*H_ + kc);
    *(short8v*)(lAlo + r*136 + kc) = *(const short8v*)(Alo + (size_t)(row0 + r)*H_ + kc);
  }

  short8v bhi[2][4], blo[2][4];
  #pragma unroll
  for (int ct = 0; ct < 2; ++ct) {
    int col = wid*32 + ct*16 + c;
    #pragma unroll
    for (int kb = 0; kb < 4; ++kb) {
      size_t o = (size_t)col*H_ + kb*32 + g*8;
      bhi[ct][kb] = *(const short8v*)(WThi + o);
      blo[ct][kb] = *(const short8v*)(WTlo + o);
    }
  }

  floatx4 acc[4][2];
  #pragma unroll
  for (int rt = 0; rt < 4; ++rt)
    #pragma unroll
    for (int ct = 0; ct < 2; ++ct)
      acc[rt][ct] = (floatx4){0.f, 0.f, 0.f, 0.f};

  __syncthreads();

  #pragma unroll
  for (int kb = 0; kb < 4; ++kb) {
    short8v ahi[4], alo[4];
    #pragma unroll
    for (int rt = 0; rt < 4; ++rt) {
      int r = rt*16 + c;
      ahi[rt] = *(const short8v*)(lAhi + r*136 + kb*32 + g*8);
      alo[rt] = *(const short8v*)(lAlo + r*136 + kb*32 + g*8);
    }
    #pragma unroll
    for (int rt = 0; rt < 4; ++rt)
      #pragma unroll
      for (int ct = 0; ct < 2; ++ct) {
        acc[rt][ct] = __builtin_amdgcn_mfma_f32_16x16x32_bf16(ahi[rt], bhi[ct][kb], acc[rt][ct], 0, 0, 0);
        acc[rt][ct] = __builtin_amdgcn_mfma_f32_16x16x32_bf16(alo[rt], bhi[ct][kb], acc[rt][ct], 0, 0, 0);
        acc[rt][ct] = __builtin_amdgcn_mfma_f32_16x16x32_bf16(ahi[rt], blo[ct][kb], acc[rt][ct], 0, 0, 0);
      }
  }

  #pragma unroll
  for (int rt = 0; rt < 4; ++rt)
    #pragma unroll
    for (int i = 0; i < 4; ++i) {
      int row = row0 + rt*16 + g*4 + i;
      if (Cb) {
        unsigned short* cr = Cb + (size_t)row*H_ + wid*32;
        cr[c]      = bf16_rne(acc[rt][0][i]);
        cr[16 + c] = bf16_rne(acc[rt][1][i]);
      } else {
        float* cr = C + (size_t)row*H_ + wid*32;
        cr[c]      = acc[rt][0][i];
        cr[16 + c] = acc[rt][1][i];
      }
    }

  if (el) {
    float av0 = al[wid*32 + c], av1 = al[wid*32 + 16 + c];
    float rv0 = ar[wid*32 + c], rv1 = ar[wid*32 + 16 + c];
    #pragma unroll
    for (int rt = 0; rt < 4; ++rt)
      #pragma unroll
      for (int i = 0; i < 4; ++i) {
        float pl = acc[rt][0][i]*av0 + acc[rt][1][i]*av1;
        float pr = acc[rt][0][i]*rv0 + acc[rt][1][i]*rv1;
        pl += __shfl_xor(pl, 1, 64); pl += __shfl_xor(pl, 2, 64);
        pl += __shfl_xor(pl, 4, 64); pl += __shfl_xor(pl, 8, 64);
        pr += __shfl_xor(pr, 1, 64); pr += __shfl_xor(pr, 2, 64);
        pr += __shfl_xor(pr, 4, 64); pr += __shfl_xor(pr, 8, 64);
        if (c == 0) { redl[wid][rt*16 + g*4 + i] = pl; redr[wid][rt*16 + g*4 + i] = pr; }
      }
    __syncthreads();
    if (t < 64) {
      el[row0 + t] = redl[0][t] + redl[1][t] + redl[2][t] + redl[3][t];
      er[row0 + t] = redr[0][t] + redr[1][t] + redr[2][t] + redr[3][t];
    }
  }
}

// ---------- FUSED A1-MFMA + attention v2: LDS relay (no atomics) ----------
__global__ __launch_bounds__(256) void k_mfma_attn(
    const unsigned short* __restrict__ Ahi, const unsigned short* __restrict__ Alo,
    const unsigned short* __restrict__ WThi, const unsigned short* __restrict__ WTlo,
    const float* __restrict__ A2, const float* __restrict__ v_attn,
    const int* __restrict__ vnr_VNF, const int* __restrict__ net_VNF,
    float* __restrict__ pi) {
  __shared__ unsigned short lA[2][64*136];   // staging; reused as f32 A1 tile [64][132]
  __shared__ float a2s2[2][10][128];         // 2*A2 for the <=2 batches this block spans
  __shared__ float vv2s[128];                // 2*v
  int t = threadIdx.x;
  int row0 = blockIdx.x * 64;
  int wid = t >> 6, lane = t & 63;
  int g = lane >> 4, c = lane & 15;
  int b0 = row0 / NN_;
  int b1 = (row0 + 63) / NN_; if (b1 > B_-1) b1 = B_-1;

  unsigned short* lAhi = lA[0];
  unsigned short* lAlo = lA[1];
  #pragma unroll
  for (int i = 0; i < 4; ++i) {
    int m = t + 256*i;
    int r = m >> 4;
    int kc = (m & 15) * 8;
    *(short8v*)(lAhi + r*136 + kc) = *(const short8v*)(Ahi + (size_t)(row0 + r)*H_ + kc);
    *(short8v*)(lAlo + r*136 + kc) = *(const short8v*)(Alo + (size_t)(row0 + r)*H_ + kc);
  }
  // stage 2*A2 for both candidate batches (each slab is 10*128=1280 floats)
  for (int i = t; i < 2560; i += 256) {
    int w = (i >= 1280) ? 1 : 0;
    int rem = i - w*1280;
    int s = rem >> 7, k = rem & 127;
    int b = (w == 0) ? b0 : b1;
    a2s2[w][s][k] = 2.f*A2[((size_t)s*B_ + b)*H_ + k];
  }
  if (t < 128) vv2s[t] = 2.f*v_attn[t];

  short8v bhi[2][4], blo[2][4];
  #pragma unroll
  for (int ct = 0; ct < 2; ++ct) {
    int col = wid*32 + ct*16 + c;
    #pragma unroll
    for (int kb = 0; kb < 4; ++kb) {
      size_t o = (size_t)col*H_ + kb*32 + g*8;
      bhi[ct][kb] = *(const short8v*)(WThi + o);
      blo[ct][kb] = *(const short8v*)(WTlo + o);
    }
  }

  floatx4 acc[4][2];
  #pragma unroll
  for (int rt = 0; rt < 4; ++rt)
    #pragma unroll
    for (int ct = 0; ct < 2; ++ct)
      acc[rt][ct] = (floatx4){0.f, 0.f, 0.f, 0.f};

  __syncthreads();

  #pragma unroll
  for (int kb = 0; kb < 4; ++kb) {
    short8v ahi[4], alo[4];
    #pragma unroll
    for (int rt = 0; rt < 4; ++rt) {
      int r = rt*16 + c;
      ahi[rt] = *(const short8v*)(lAhi + r*136 + kb*32 + g*8);
      alo[rt] = *(const short8v*)(lAlo + r*136 + kb*32 + g*8);
    }
    #pragma unroll
    for (int rt = 0; rt < 4; ++rt)
      #pragma unroll
      for (int ct = 0; ct < 2; ++ct) {
        acc[rt][ct] = __builtin_amdgcn_mfma_f32_16x16x32_bf16(ahi[rt], bhi[ct][kb], acc[rt][ct], 0, 0, 0);
        acc[rt][ct] = __builtin_amdgcn_mfma_f32_16x16x32_bf16(alo[rt], bhi[ct][kb], acc[rt][ct], 0, 0, 0);
        acc[rt][ct] = __builtin_amdgcn_mfma_f32_16x16x32_bf16(ahi[rt], blo[ct][kb], acc[rt][ct], 0, 0, 0);
      }
  }

  __syncthreads();   // all waves done reading staging LDS

  // relay: write f32 A1 tile (stride 132 words; 2-way bank aliasing only)
  float* a1s = (float*)lA;
  #pragma unroll
  for (int rt = 0; rt < 4; ++rt)
    #pragma unroll
    for (int i = 0; i < 4; ++i) {
      int lrow = rt*16 + g*4 + i;
      a1s[lrow*132 + wid*32 + c]      = acc[rt][0][i];
      a1s[lrow*132 + wid*32 + 16 + c] = acc[rt][1][i];
    }
  __syncthreads();

  // attn3 epilogue: thread owns (row nl, quarter p)
  int nl = t >> 2, p = t & 3;
  int row = row0 + nl;
  int b = row / NN_, n = row - b*NN_;
  int w = (b != b0) ? 1 : 0;
  const float* arow = a1s + nl*132 + p*32;
  float4 a[8], w2[8];
  #pragma unroll
  for (int kk = 0; kk < 8; ++kk) {
    float4 av = *(const float4*)(arow + kk*4);
    a[kk] = make_float4(2.f*av.x, 2.f*av.y, 2.f*av.z, 2.f*av.w);
    w2[kk] = *(const float4*)(&vv2s[p*32 + kk*4]);
  }
  float vsum = 0.f;
  #pragma unroll
  for (int kk = 0; kk < 8; ++kk)
    vsum += (w2[kk].x + w2[kk].y) + (w2[kk].z + w2[kk].w);
  vsum *= 0.5f;
  float accs[10];
  #pragma unroll
  for (int s = 0; s < 10; ++s) {
    const float* a2r = &a2s2[w][s][p*32];
    float sum2 = 0.f;
    #pragma unroll
    for (int kk = 0; kk < 8; ++kk) {
      float4 cc = *(const float4*)(a2r + kk*4);
      sum2 = fmaf(w2[kk].x, fast_rcp(1.f + __expf(a[kk].x + cc.x)), sum2);
      sum2 = fmaf(w2[kk].y, fast_rcp(1.f + __expf(a[kk].y + cc.y)), sum2);
      sum2 = fmaf(w2[kk].z, fast_rcp(1.f + __expf(a[kk].z + cc.z)), sum2);
      sum2 = fmaf(w2[kk].w, fast_rcp(1.f + __expf(a[kk].w + cc.w)), sum2);
    }
    accs[s] = vsum - sum2;
  }
  #pragma unroll
  for (int s = 0; s < 10; ++s) {
    accs[s] += __shfl_xor(accs[s], 1, 64);
    accs[s] += __shfl_xor(accs[s], 2, 64);
  }
  if (p == 0) {
    #pragma unroll
    for (int s = 0; s < 10; ++s) {
      int vnf = vnr_VNF[b*NV_ + s];
      int m   = net_VNF[(size_t)row*T_ + vnf];
      pi[(size_t)b*(NV_*NN_) + (size_t)s*NN_ + n] = accs[s] + __logf((float)m);
    }
  }
}

// ---------- FUSED aggregate -> MFMA GEMM (vnr path only: 10 blocks, tiny) ----------
__global__ __launch_bounds__(256) void k_agg_mfma(
    const int* __restrict__ rowptr, const unsigned short* __restrict__ srcp,
    const float* __restrict__ el_in, const float* __restrict__ er_in,
    const unsigned short* __restrict__ z_in, const float* __restrict__ bias,
    const unsigned short* __restrict__ WThi, const unsigned short* __restrict__ WTlo,
    unsigned short* __restrict__ zb_out, float* __restrict__ Cf,
    const float* __restrict__ al, const float* __restrict__ ar,
    float* __restrict__ el_out, float* __restrict__ er_out) {
  __shared__ unsigned short lAhi[64*136];
  __shared__ unsigned short lAlo[64*136];
  __shared__ float redl[4][64];
  __shared__ float redr[4][64];
  int t = threadIdx.x;
  int row0 = blockIdx.x * 64;
  int wid = t >> 6, lane = t & 63;
  int g = lane >> 4, c = lane & 15;

  float b0 = bias[lane*2], b1 = bias[lane*2 + 1];

  for (int j = 0; j < 8; ++j) {
    int wA = row0 + wid*16 + 2*j;
    int wB = wA + 1;
    int begA = rowptr[wA], endA = rowptr[wA+1];
    int begB = rowptr[wB], endB = rowptr[wB+1];
    float erA = er_in[wA], erB = er_in[wB];
    float a0A = 0.f, a1A = 0.f, wsA = 0.f;
    float a0B = 0.f, a1B = 0.f, wsB = 0.f;
    int iA = begA, iB = begB;
    while (iA < endA || iB < endB) {
      int sA[8], sB[8];
      #pragma unroll
      for (int u = 0; u < 8; ++u) {
        sA[u] = (iA + u < endA) ? (int)srcp[iA + u] : 0;
        sB[u] = (iB + u < endB) ? (int)srcp[iB + u] : 0;
      }
      float lA[8], lB[8];
      #pragma unroll
      for (int u = 0; u < 8; ++u) { lA[u] = el_in[sA[u]]; lB[u] = el_in[sB[u]]; }
      ushort2 qA[8], qB[8];
      #pragma unroll
      for (int u = 0; u < 8; ++u) {
        qA[u] = *(const ushort2*)(z_in + (size_t)sA[u]*H_ + lane*2);
        qB[u] = *(const ushort2*)(z_in + (size_t)sB[u]*H_ + lane*2);
      }
      #pragma unroll
      for (int u = 0; u < 8; ++u) {
        float wtA = (iA + u < endA) ? __expf(lrelu02(lA[u] + erA)) : 0.f;
        float wtB = (iB + u < endB) ? __expf(lrelu02(lB[u] + erB)) : 0.f;
        a0A += wtA*bf16_tof(qA[u].x); a1A += wtA*bf16_tof(qA[u].y); wsA += wtA;
        a0B += wtB*bf16_tof(qB[u].x); a1B += wtB*bf16_tof(qB[u].y); wsB += wtB;
      }
      iA += 8; iB += 8;
    }
    float invA = (endA > begA) ? fast_rcp(wsA) : 0.f;
    float invB = (endB > begB) ? fast_rcp(wsB) : 0.f;
    float o0A = a0A*invA + b0, o1A = a1A*invA + b1;
    float o0B = a0B*invB + b0, o1B = a1B*invB + b1;
    int rA = wid*16 + 2*j;
    unsigned short hA0 = bf16_rne(o0A), hA1 = bf16_rne(o1A);
    unsigned short hB0 = bf16_rne(o0B), hB1 = bf16_rne(o1B);
    ushort2 hvA; hvA.x = hA0; hvA.y = hA1;
    ushort2 lvA; lvA.x = bf16_rne(o0A - bf16_tof(hA0)); lvA.y = bf16_rne(o1A - bf16_tof(hA1));
    ushort2 hvB; hvB.x = hB0; hvB.y = hB1;
    ushort2 lvB; lvB.x = bf16_rne(o0B - bf16_tof(hB0)); lvB.y = bf16_rne(o1B - bf16_tof(hB1));
    *(ushort2*)(lAhi + rA*136 + lane*2) = hvA;
    *(ushort2*)(lAlo + rA*136 + lane*2) = lvA;
    *(ushort2*)(lAhi + (rA+1)*136 + lane*2) = hvB;
    *(ushort2*)(lAlo + (rA+1)*136 + lane*2) = lvB;
  }

  short8v bhi[2][4], blo[2][4];
  #pragma unroll
  for (int ct = 0; ct < 2; ++ct) {
    int col = wid*32 + ct*16 + c;
    #pragma unroll
    for (int kb = 0; kb < 4; ++kb) {
      size_t o = (size_t)col*H_ + kb*32 + g*8;
      bhi[ct][kb] = *(const short8v*)(WThi + o);
      blo[ct][kb] = *(const short8v*)(WTlo + o);
    }
  }

  floatx4 acc[4][2];
  #pragma unroll
  for (int rt = 0; rt < 4; ++rt)
    #pragma unroll
    for (int ct = 0; ct < 2; ++ct)
      acc[rt][ct] = (floatx4){0.f, 0.f, 0.f, 0.f};

  __syncthreads();

  #pragma unroll
  for (int kb = 0; kb < 4; ++kb) {
    short8v ahi[4], alo[4];
    #pragma unroll
    for (int rt = 0; rt < 4; ++rt) {
      int r = rt*16 + c;
      ahi[rt] = *(const short8v*)(lAhi + r*136 + kb*32 + g*8);
      alo[rt] = *(const short8v*)(lAlo + r*136 + kb*32 + g*8);
    }
    #pragma unroll
    for (int rt = 0; rt < 4; ++rt)
      #pragma unroll
      for (int ct = 0; ct < 2; ++ct) {
        acc[rt][ct] = __builtin_amdgcn_mfma_f32_16x16x32_bf16(ahi[rt], bhi[ct][kb], acc[rt][ct], 0, 0, 0);
        acc[rt][ct] = __builtin_amdgcn_mfma_f32_16x16x32_bf16(alo[rt], bhi[ct][kb], acc[rt][ct], 0, 0, 0);
        acc[rt][ct] = __builtin_amdgcn_mfma_f32_16x16x32_bf16(ahi[rt], blo[ct][kb], acc[rt][ct], 0, 0, 0);
      }
  }

  #pragma unroll
  for (int rt = 0; rt < 4; ++rt)
    #pragma unroll
    for (int i = 0; i < 4; ++i) {
      int row = row0 + rt*16 + g*4 + i;
      if (zb_out) {
        unsigned short* cr = zb_out + (size_t)row*H_ + wid*32;
        cr[c]      = bf16_rne(acc[rt][0][i]);
        cr[16 + c] = bf16_rne(acc[rt][1][i]);
      } else {
        float* cr = Cf + (size_t)row*H_ + wid*32;
        cr[c]      = acc[rt][0][i];
        cr[16 + c] = acc[rt][1][i];
      }
    }

  if (el_out) {
    float av0 = al[wid*32 + c], av1 = al[wid*32 + 16 + c];
    float rv0 = ar[wid*32 + c], rv1 = ar[wid*32 + 16 + c];
    #pragma unroll
    for (int rt = 0; rt < 4; ++rt)
      #pragma unroll
      for (int i = 0; i < 4; ++i) {
        float pl = acc[rt][0][i]*av0 + acc[rt][1][i]*av1;
        float pr = acc[rt][0][i]*rv0 + acc[rt][1][i]*rv1;
        pl += __shfl_xor(pl, 1, 64); pl += __shfl_xor(pl, 2, 64);
        pl += __shfl_xor(pl, 4, 64); pl += __shfl_xor(pl, 8, 64);
        pr += __shfl_xor(pr, 1, 64); pr += __shfl_xor(pr, 2, 64);
        pr += __shfl_xor(pr, 4, 64); pr += __shfl_xor(pr, 8, 64);
        if (c == 0) { redl[wid][rt*16 + g*4 + i] = pl; redr[wid][rt*16 + g*4 + i] = pr; }
      }
    __syncthreads();
    if (t < 64) {
      el_out[row0 + t] = redl[0][t] + redl[1][t] + redl[2][t] + redl[3][t];
      er_out[row0 + t] = redr[0][t] + redr[1][t] + redr[2][t] + redr[3][t];
    }
  }
}

// ---------- plain aggregate: bf16 z in, f32 out (vnr layer 3) ----------
__global__ __launch_bounds__(256) void k_aggregate_f(int nNodes, const int* __restrict__ rowptr,
    const unsigned short* __restrict__ srcp, const float* __restrict__ el,
    const float* __restrict__ er, const unsigned short* __restrict__ z,
    const float* __restrict__ bias, float* __restrict__ out) {
  int w = (blockIdx.x*256 + threadIdx.x) >> 6;
  int lane = threadIdx.x & 63;
  if (w >= nNodes) return;
  int beg = rowptr[w], end = rowptr[w+1];
  float erw = er[w];
  float a0 = 0.f, a1 = 0.f, wsum = 0.f;
  for (int i = beg; i < end; ++i) {
    int sI = srcp[i];
    float wt = __expf(lrelu02(el[sI] + erw));
    ushort2 q = *(const ushort2*)(z + (size_t)sI*H_ + lane*2);
    a0 += wt*bf16_tof(q.x); a1 += wt*bf16_tof(q.y); wsum += wt;
  }
  float inv = (end > beg) ? fast_rcp(wsum) : 0.f;
  float2 o;
  o.x = a0*inv + bias[lane*2];
  o.y = a1*inv + bias[lane*2 + 1];
  *(float2*)(out + (size_t)w*H_ + lane*2) = o;
}

// ---------- generic f32 GEMM (layer-1 static, layer-1 vnr, GI) ----------
__global__ __launch_bounds__(256) void k_gemm(const float* A, int M, int K, int N,
                                              const float* W, const float* bias,
                                              float* C, unsigned short* Cb,
                                              const float* al, const float* ar,
                                              float* el, float* er) {
  __shared__ float Ws_[64*128];
  __shared__ float As_[16*128];
  __shared__ float redl[16][17];
  __shared__ float redr[16][17];
  int t = threadIdx.x;
  int j0 = blockIdx.y * 128;
  int row0 = blockIdx.x * 16;
  for (int l = t; l < 16*K; l += 256) {
    int r = l / K, k = l - r*K;
    int row = row0 + r;
    As_[r*K + k] = (row < M) ? A[(size_t)row*K + k] : 0.f;
  }
  int jg = t & 15, r = t >> 4;
  float acc[8];
  #pragma unroll
  for (int q = 0; q < 8; ++q) acc[q] = 0.f;
  for (int kc = 0; kc < K; kc += 64) {
    int kl = min(64, K - kc);
    __syncthreads();
    for (int l = t; l < (kl << 7); l += 256) {
      int k = l >> 7, j = l & 127;
      int jj = j0 + j;
      Ws_[l] = (jj < N) ? W[(size_t)(kc + k)*N + jj] : 0.f;
    }
    __syncthreads();
    for (int k = 0; k < kl; ++k) {
      float a = As_[r*K + kc + k];
      const float* wr = &Ws_[(k << 7) + jg*8];
      #pragma unroll
      for (int q = 0; q < 8; ++q) acc[q] += a * wr[q];
    }
  }
  int row = row0 + r;
  if (row < M) {
    if (Cb) {
      unsigned short* crow = Cb + (size_t)row*N + j0 + jg*8;
      #pragma unroll
      for (int q = 0; q < 8; ++q) {
        int j = j0 + jg*8 + q;
        if (j < N) crow[q] = bf16_rne(acc[q] + (bias ? bias[j] : 0.f));
      }
    } else {
      float* crow = C + (size_t)row*N + j0 + jg*8;
      #pragma unroll
      for (int q = 0; q < 8; ++q) {
        int j = j0 + jg*8 + q;
        if (j < N) crow[q] = acc[q] + (bias ? bias[j] : 0.f);
      }
    }
  }
  if (el) {
    float pl = 0.f, pr = 0.f;
    #pragma unroll
    for (int q = 0; q < 8; ++q) {
      int j = jg*8 + q;
      pl += acc[q]*al[j];
      pr += acc[q]*ar[j];
    }
    redl[r][jg] = pl; redr[r][jg] = pr;
    __syncthreads();
    if (t < 16) {
      float sl = 0.f, sr = 0.f;
      for (int q = 0; q < 16; ++q) { sl += redl[t][q]; sr += redr[t][q]; }
      int row2 = row0 + t;
      if (row2 < M) { el[row2] = sl; er[row2] = sr; }
    }
  }
}

// ---------- GRU decoder: weights register-resident, LDS-broadcast h ----------
__global__ __launch_bounds__(512) void k_decoder(const float* __restrict__ GI,
                                                 const float* __restrict__ W_hh,
                                                 const float* __restrict__ b_hh,
                                                 const float* __restrict__ W_attn,
                                                 const float* __restrict__ h0,
                                                 float* __restrict__ A2) {
  int b = blockIdx.x;
  __shared__ float h[128];
  __shared__ float gh[384];
  int t = threadIdx.x;
  const float4* wsrc = (t < 384)
      ? (const float4*)(W_hh + (size_t)t*128)
      : (const float4*)(W_attn + (size_t)(t-384)*256 + 128);
  float4 wreg[32];
  #pragma unroll
  for (int kk = 0; kk < 32; ++kk) wreg[kk] = wsrc[kk];
  float bh = (t < 384) ? b_hh[t] : 0.f;
  if (t < 128) h[t] = h0[t];
  __syncthreads();
  for (int s = 0; s < 10; ++s) {
    const float4* h4 = (const float4*)h;
    if (t < 384) {
      float a0 = 0.f, a1 = 0.f, a2 = 0.f, a3 = 0.f;
      #pragma unroll
      for (int kk = 0; kk < 32; kk += 4) {
        a0 += dot4(wreg[kk+0], h4[kk+0]);
        a1 += dot4(wreg[kk+1], h4[kk+1]);
        a2 += dot4(wreg[kk+2], h4[kk+2]);
        a3 += dot4(wreg[kk+3], h4[kk+3]);
      }
      gh[t] = (a0 + a1) + (a2 + a3) + bh;
    }
    __syncthreads();
    if (t < 128) {
      const float* gi = GI + (size_t)(b*NV_ + s)*384;
      float rr = fast_sigmoid(gi[t]       + gh[t]);
      float zz = fast_sigmoid(gi[128 + t] + gh[128 + t]);
      float nn = fast_tanh   (gi[256 + t] + rr*gh[256 + t]);
      h[t] = (1.f - zz)*nn + zz*h[t];
    }
    __syncthreads();
    if (t >= 384) {
      float a0 = 0.f, a1 = 0.f, a2 = 0.f, a3 = 0.f;
      #pragma unroll
      for (int kk = 0; kk < 32; kk += 4) {
        a0 += dot4(wreg[kk+0], h4[kk+0]);
        a1 += dot4(wreg[kk+1], h4[kk+1]);
        a2 += dot4(wreg[kk+2], h4[kk+2]);
        a3 += dot4(wreg[kk+3], h4[kk+3]);
      }
      A2[((size_t)s*B_ + b)*128 + (t - 384)] = (a0 + a1) + (a2 + a3);
    }
  }
}

// ---------- value head ----------
__global__ __launch_bounds__(128) void k_y2s(const unsigned short* hi, const unsigned short* lo,
                                             float* y2) {
  int b = blockIdx.x, slice = blockIdx.y, h = threadIdx.x;
  int n0 = slice*125, n1 = n0 + 125;
  float s = 0.f;
  for (int n = n0; n < n1; ++n) {
    size_t idx = ((size_t)b*NN_ + n)*H_ + h;
    s += bf16_tof(hi[idx]) + bf16_tof(lo[idx]);
  }
  atomicAdd(&y2[b*H_ + h], s);
}

__global__ __launch_bounds__(128) void k_value(const float* __restrict__ Hv,
                                               const float* __restrict__ nmask,
                                               const float* __restrict__ y2,
                                               const float* __restrict__ W_out,
                                               const float* __restrict__ b_out,
                                               float* __restrict__ val) {
  __shared__ float y1s[128];
  int b = blockIdx.x, t = threadIdx.x;
  float s = 0.f, d = 0.f;
  #pragma unroll
  for (int i = 0; i < NV_; ++i) {
    float m = nmask[b*NV_ + i];
    s += Hv[(size_t)(b*NV_ + i)*H_ + t]*m;
    d += m;
  }
  y1s[t] = s/d;
  __syncthreads();
  if (t < 64) {
    const float* w = W_out + (size_t)t*256;
    float acc = b_out[t];
    for (int h = 0; h < H_; ++h)
      acc += y1s[h]*w[h] + (y2[b*H_ + h]*(1.f/1000.f))*w[128 + h];
    val[b*O_ + t] = acc;
  }
}

extern "C" void kernel_launch(void* const* d_in, const int* in_sizes, int n_in,
                              void* d_out, int out_size, void* d_ws, size_t ws_size,
                              hipStream_t stream) {
  (void)in_sizes; (void)n_in; (void)out_size; (void)ws_size;
  const float* static_feat = (const float*)d_in[0];
  const float* vnr_feat    = (const float*)d_in[1];
  const float* nmask       = (const float*)d_in[2];
  const float* Ws1 = (const float*)d_in[3];  const float* als1 = (const float*)d_in[4];
  const float* ars1 = (const float*)d_in[5]; const float* bs1 = (const float*)d_in[6];
  const float* Ws2 = (const float*)d_in[7];  const float* als2 = (const float*)d_in[8];
  const float* ars2 = (const float*)d_in[9]; const float* bs2 = (const float*)d_in[10];
  const float* Ws3 = (const float*)d_in[11]; const float* als3 = (const float*)d_in[12];
  const float* ars3 = (const float*)d_in[13]; const float* bs3 = (const float*)d_in[14];
  const float* Wv1 = (const float*)d_in[15]; const float* alv1 = (const float*)d_in[16];
  const float* arv1 = (const float*)d_in[17]; const float* bv1 = (const float*)d_in[18];
  const float* Wv2 = (const float*)d_in[19]; const float* alv2 = (const float*)d_in[20];
  const float* arv2 = (const float*)d_in[21]; const float* bv2 = (const float*)d_in[22];
  const float* Wv3 = (const float*)d_in[23]; const float* alv3 = (const float*)d_in[24];
  const float* arv3 = (const float*)d_in[25]; const float* bv3 = (const float*)d_in[26];
  const float* W_attn = (const float*)d_in[27];
  const float* v_attn = (const float*)d_in[28];
  const float* W_ih = (const float*)d_in[29];
  const float* W_hh = (const float*)d_in[30];
  const float* b_ih = (const float*)d_in[31];
  const float* b_hh = (const float*)d_in[32];
  const float* h0   = (const float*)d_in[33];
  const float* W_out = (const float*)d_in[34];
  const float* b_out = (const float*)d_in[35];
  const int* src_s = (const int*)d_in[36];
  const int* dst_s = (const int*)d_in[37];
  const int* src_v = (const int*)d_in[38];
  const int* dst_v = (const int*)d_in[39];
  const int* vnr_VNF = (const int*)d_in[40];
  const int* net_VNF = (const int*)d_in[41];

  char* ws = (char*)d_ws;
  size_t off = 0;
  auto alloc = [&](size_t bytes) -> char* {
    off = (off + 255) & ~(size_t)255;
    char* p = ws + off;
    off += bytes;
    return p;
  };
  unsigned short* Zb0 = (unsigned short*)alloc((size_t)NS_*H_*2);   // bf16 z
  unsigned short* HsHi = (unsigned short*)alloc((size_t)NS_*H_*2);
  unsigned short* HsLo = (unsigned short*)alloc((size_t)NS_*H_*2);
  unsigned short* Zbv0 = (unsigned short*)alloc((size_t)NVT_*H_*2);
  unsigned short* Zbv1 = (unsigned short*)alloc((size_t)NVT_*H_*2);
  float* Hv   = (float*)alloc((size_t)NVT_*H_*4);
  float* el_s = (float*)alloc((size_t)NS_*4);
  float* er_s = (float*)alloc((size_t)NS_*4);
  float* elv_a = (float*)alloc((size_t)NVT_*4);
  float* erv_a = (float*)alloc((size_t)NVT_*4);
  float* elv_b = (float*)alloc((size_t)NVT_*4);
  float* erv_b = (float*)alloc((size_t)NVT_*4);
  size_t zcount = (size_t)NS_ + NS_ + NVT_ + NVT_ + B_*H_;
  char* zb = alloc(zcount*4);
  int*   counts_s = (int*)zb;
  int*   cursor_s = counts_s + NS_;
  int*   counts_v = cursor_s + NS_;
  int*   cursor_v = counts_v + NVT_;
  float* y2buf    = (float*)(cursor_v + NVT_);
  int* rowptr_s = (int*)alloc((size_t)(NS_+1)*4);
  int* rowptr_v = (int*)alloc((size_t)(NVT_+1)*4);
  int* bsum     = (int*)alloc((size_t)256*4);
  unsigned short* srcp_s = (unsigned short*)alloc((size_t)(EN_+8)*2);
  unsigned short* srcp_v = (unsigned short*)alloc((size_t)(EV_+8)*2);
  unsigned short* WS2hi = (unsigned short*)alloc((size_t)H_*H_*2);
  unsigned short* WS2lo = (unsigned short*)alloc((size_t)H_*H_*2);
  unsigned short* WS3hi = (unsigned short*)alloc((size_t)H_*H_*2);
  unsigned short* WS3lo = (unsigned short*)alloc((size_t)H_*H_*2);
  unsigned short* WAhi  = (unsigned short*)alloc((size_t)H_*H_*2);
  unsigned short* WAlo  = (unsigned short*)alloc((size_t)H_*H_*2);
  unsigned short* WV2hi = (unsigned short*)alloc((size_t)H_*H_*2);
  unsigned short* WV2lo = (unsigned short*)alloc((size_t)H_*H_*2);
  unsigned short* WV3hi = (unsigned short*)alloc((size_t)H_*H_*2);
  unsigned short* WV3lo = (unsigned short*)alloc((size_t)H_*H_*2);
  float* WTih   = (float*)alloc((size_t)H_*384*4);
  float* GI     = (float*)alloc((size_t)NVT_*384*4);
  float* A2     = (float*)alloc((size_t)NV_*B_*H_*4);

  float* pi  = (float*)d_out;
  float* val = pi + (size_t)B_*NV_*NN_;

  hipMemsetAsync(zb, 0, zcount*4, stream);

  k_prep<<<dim3(192, 6), 256, 0, stream>>>(W_ih, Ws2, Ws3, W_attn, Wv2, Wv3, WTih,
                                           WS2hi, WS2lo, WS3hi, WS3lo, WAhi, WAlo,
                                           WV2hi, WV2lo, WV3hi, WV3lo);

  // CSR build: XCD-ranged count + scatter
  int edgeChunks = (EN_ + EV_ + 255)/256;
  k_count_r<<<edgeChunks*8, 256, 0, stream>>>(dst_s, dst_v, counts_s, counts_v);
  k_scan_local<<<250, 256, 0, stream>>>(counts_s, NS_, rowptr_s, bsum);
  k_scan_small<<<2, 1024, 0, stream>>>(bsum, 250, counts_v, rowptr_v, NVT_);
  k_scan_add<<<250, 256, 0, stream>>>(rowptr_s, bsum, NS_, EN_);
  k_scatter_r<<<edgeChunks*8, 256, 0, stream>>>(src_s, dst_s, src_v, dst_v,
                                                rowptr_s, rowptr_v, cursor_s, cursor_v,
                                                srcp_s, srcp_v);

  int aggS = (NS_ + 7)/8;   // 2 nodes/wave, 4 waves/block -> 8 nodes/block

  // ---- static GAT stack ----
  k_gemm<<<dim3(NS_/16, 1), 256, 0, stream>>>(static_feat, NS_, FS_, H_, Ws1, nullptr,
                                              nullptr, Zb0, als1, ars1, el_s, er_s);
  k_aggregate_split<<<aggS, 256, 0, stream>>>(NS_, rowptr_s, srcp_s, el_s, er_s, Zb0, bs1, HsHi, HsLo);
  k_mfma_gemm<<<NS_/64, 256, 0, stream>>>(HsHi, HsLo, WS2hi, WS2lo, nullptr, Zb0, als2, ars2, el_s, er_s);
  k_aggregate_split<<<aggS, 256, 0, stream>>>(NS_, rowptr_s, srcp_s, el_s, er_s, Zb0, bs2, HsHi, HsLo);
  k_mfma_gemm<<<NS_/64, 256, 0, stream>>>(HsHi, HsLo, WS3hi, WS3lo, nullptr, Zb0, als3, ars3, el_s, er_s);
  k_aggregate_split<<<aggS, 256, 0, stream>>>(NS_, rowptr_s, srcp_s, el_s, er_s, Zb0, bs3, HsHi, HsLo);
  k_y2s<<<dim3(B_, 8), 128, 0, stream>>>(HsHi, HsLo, y2buf);

  // ---- vnr GAT stack (tiny: fused agg+GEMM, 10 blocks) ----
  k_gemm<<<dim3(NVT_/16, 1), 256, 0, stream>>>(vnr_feat, NVT_, FV_, H_, Wv1, nullptr,
                                               nullptr, Zbv0, alv1, arv1, elv_a, erv_a);
  k_agg_mfma<<<NVT_/64, 256, 0, stream>>>(rowptr_v, srcp_v, elv_a, erv_a, Zbv0, bv1,
                                          WV2hi, WV2lo, Zbv1, nullptr,
                                          alv2, arv2, elv_b, erv_b);
  k_agg_mfma<<<NVT_/64, 256, 0, stream>>>(rowptr_v, srcp_v, elv_b, erv_b, Zbv1, bv2,
                                          WV3hi, WV3lo, Zbv0, nullptr,
                                          alv3, arv3, elv_a, erv_a);
  k_aggregate_f<<<(NVT_ + 3)/4, 256, 0, stream>>>(NVT_, rowptr_v, srcp_v, elv_a, erv_a,
                                                  Zbv0, bv3, Hv);

  // ---- decoder ----
  k_gemm<<<dim3(NVT_/16, 3), 256, 0, stream>>>(Hv, NVT_, H_, 384, WTih, b_ih, GI, nullptr,
                                               nullptr, nullptr, nullptr, nullptr);
  k_decoder<<<B_, 512, 0, stream>>>(GI, W_hh, b_hh, W_attn, h0, A2);
  // fused A1-MFMA + attention (LDS relay; no Z round trip, no atomics)
  k_mfma_attn<<<NS_/64, 256, 0, stream>>>(HsHi, HsLo, WAhi, WAlo, A2, v_attn,
                                          vnr_VNF, net_VNF, pi);

  // ---- value head ----
  k_value<<<B_, 128, 0, stream>>>(Hv, nmask, y2buf, W_out, b_out, val);
}

// Round 16
// 380.832 us; speedup vs baseline: 1.7233x; 1.0188x over previous
//
#include <hip/hip_runtime.h>
#include <hip/hip_bf16.h>
#include <math.h>

#define B_   64
#define NN_  1000
#define NV_  10
#define H_   128
#define FS_  8
#define FV_  6
#define T_   8
#define O_   64
#define EN_  512000
#define EV_  2560
#define NS_  (B_*NN_)   /* 64000 */
#define NVT_ (B_*NV_)   /* 640 */
#define RNG_S (NS_/8)   /* 8000 dst nodes per XCD range */
#define RNG_V (NVT_/8)  /* 80 */

typedef __attribute__((ext_vector_type(8))) short short8v;   // 8 bf16
typedef __attribute__((ext_vector_type(4))) float floatx4;

__device__ __forceinline__ float fast_rcp(float x) { return __builtin_amdgcn_rcpf(x); }
__device__ __forceinline__ float fast_tanh(float x) {
  return 1.f - 2.f*fast_rcp(1.f + __expf(2.f*x));
}
__device__ __forceinline__ float fast_sigmoid(float x) {
  return fast_rcp(1.f + __expf(-x));
}
__device__ __forceinline__ unsigned short bf16_rne(float x) {
  unsigned u = __float_as_uint(x);
  return (unsigned short)((u + 0x7FFFu + ((u >> 16) & 1u)) >> 16);
}
__device__ __forceinline__ float bf16_tof(unsigned short b) {
  return __uint_as_float(((unsigned)b) << 16);
}
__device__ __forceinline__ float dot4(float4 a, float4 b) {
  return a.x*b.x + a.y*b.y + a.z*b.z + a.w*b.w;
}
__device__ __forceinline__ float lrelu02(float e) {
  return (e > 0.f) ? e : 0.2f*e;
}

// ---------- CSR build: XCD-ranged count (atomics stay in one XCD's L2) ----------
__global__ __launch_bounds__(256) void k_count_r(const int* __restrict__ dst_s,
                                                 const int* __restrict__ dst_v,
                                                 int* __restrict__ counts_s,
                                                 int* __restrict__ counts_v) {
  int bid = blockIdx.x;
  int r = bid & 7;
  int i = (bid >> 3)*256 + threadIdx.x;
  if (i < EN_) {
    int d = dst_s[i];
    int lo = r*RNG_S;
    if (d >= lo && d < lo + RNG_S) atomicAdd(&counts_s[d], 1);
  } else if (i < EN_ + EV_) {
    int d = dst_v[i - EN_];
    int lo = r*RNG_V;
    if (d >= lo && d < lo + RNG_V) atomicAdd(&counts_v[d], 1);
  }
}

__global__ __launch_bounds__(256) void k_scan_local(const int* cnt, int n, int* out, int* bsum) {
  __shared__ int s[256];
  int t = threadIdx.x; int i = blockIdx.x*256 + t;
  int v = (i < n) ? cnt[i] : 0;
  s[t] = v; __syncthreads();
  #pragma unroll
  for (int o = 1; o < 256; o <<= 1) {
    int u = (t >= o) ? s[t-o] : 0; __syncthreads();
    s[t] += u; __syncthreads();
  }
  if (i < n) out[i] = s[t] - v;
  if (t == 255) bsum[blockIdx.x] = s[255];
}

__global__ __launch_bounds__(1024) void k_scan_small(int* bsum, int nb,
                                                     const int* cntv, int* rowptr_v, int nv) {
  __shared__ int sums[1024];
  int t = threadIdx.x;
  if (blockIdx.x == 0) {
    int v = (t < nb) ? bsum[t] : 0;
    sums[t] = v; __syncthreads();
    for (int o = 1; o < 1024; o <<= 1) {
      int u = (t >= o) ? sums[t-o] : 0; __syncthreads();
      sums[t] += u; __syncthreads();
    }
    if (t < nb) bsum[t] = sums[t] - v;
  } else {
    int v = (t < nv) ? cntv[t] : 0;
    sums[t] = v; __syncthreads();
    for (int o = 1; o < 1024; o <<= 1) {
      int u = (t >= o) ? sums[t-o] : 0; __syncthreads();
      sums[t] += u; __syncthreads();
    }
    if (t < nv) rowptr_v[t] = sums[t] - v;
    if (t == nv-1) rowptr_v[nv] = sums[t];
  }
}

__global__ __launch_bounds__(256) void k_scan_add(int* out, const int* bsum, int n, int E) {
  int i = blockIdx.x*256 + threadIdx.x;
  if (i < n) out[i] += bsum[blockIdx.x];
  if (i == 0) out[n] = E;
}

__global__ __launch_bounds__(256) void k_scatter_r(const int* __restrict__ src_s,
                                                   const int* __restrict__ dst_s,
                                                   const int* __restrict__ src_v,
                                                   const int* __restrict__ dst_v,
                                                   const int* __restrict__ rowptr_s,
                                                   const int* __restrict__ rowptr_v,
                                                   int* __restrict__ cursor_s,
                                                   int* __restrict__ cursor_v,
                                                   unsigned short* __restrict__ srcp_s,
                                                   unsigned short* __restrict__ srcp_v) {
  int bid = blockIdx.x;
  int r = bid & 7;
  int i = (bid >> 3)*256 + threadIdx.x;
  if (i < EN_) {
    int d = dst_s[i];
    int lo = r*RNG_S;
    if (d >= lo && d < lo + RNG_S) {
      int pos = rowptr_s[d] + atomicAdd(&cursor_s[d], 1);
      srcp_s[pos] = (unsigned short)src_s[i];
    }
  } else if (i < EN_ + EV_) {
    int j = i - EN_;
    int d = dst_v[j];
    int lo = r*RNG_V;
    if (d >= lo && d < lo + RNG_V) {
      int pos = rowptr_v[d] + atomicAdd(&cursor_v[d], 1);
      srcp_v[pos] = (unsigned short)src_v[j];
    }
  }
}

// ---------- fused weight prep: W_ih transpose + 5x split ----------
__global__ __launch_bounds__(256) void k_prep(const float* W_ih, const float* Ws2,
                                              const float* Ws3, const float* W_attn,
                                              const float* Wv2, const float* Wv3,
                                              float* WTih,
                                              unsigned short* WS2hi, unsigned short* WS2lo,
                                              unsigned short* WS3hi, unsigned short* WS3lo,
                                              unsigned short* WAhi, unsigned short* WAlo,
                                              unsigned short* WV2hi, unsigned short* WV2lo,
                                              unsigned short* WV3hi, unsigned short* WV3lo) {
  int idx = blockIdx.x*256 + threadIdx.x;
  int task = blockIdx.y;
  if (task == 0) {
    if (idx < 128*384) {
      int k = idx / 384, j = idx - k*384;
      WTih[idx] = W_ih[(size_t)j*128 + k];
    }
  } else {
    if (idx >= 128*128) return;
    int j = idx >> 7, k = idx & 127;
    float v; unsigned short *hi, *lo;
    if (task == 1)      { v = Ws2[(size_t)k*128 + j];    hi = WS2hi; lo = WS2lo; }
    else if (task == 2) { v = Ws3[(size_t)k*128 + j];    hi = WS3hi; lo = WS3lo; }
    else if (task == 3) { v = W_attn[(size_t)j*256 + k]; hi = WAhi;  lo = WAlo;  }
    else if (task == 4) { v = Wv2[(size_t)k*128 + j];    hi = WV2hi; lo = WV2lo; }
    else                { v = Wv3[(size_t)k*128 + j];    hi = WV3hi; lo = WV3lo; }
    unsigned short h = bf16_rne(v);
    hi[idx] = h; lo[idx] = bf16_rne(v - bf16_tof(h));
  }
}

// ---------- static-path aggregate: 4 nodes/wave (16 lanes each), masked 8-batches ----------
// 32 independent gather chains in flight per wave; lane covers 8 features via
// one ushort8 (16B) load; 16 lanes still fetch exactly one 256B z-row per edge.
__global__ __launch_bounds__(256) void k_aggregate_split(int nNodes, const int* __restrict__ rowptr,
    const unsigned short* __restrict__ srcp, const float* __restrict__ el, const float* __restrict__ er,
    const unsigned short* __restrict__ z, const float* __restrict__ bias,
    unsigned short* __restrict__ outHi, unsigned short* __restrict__ outLo) {
  int wv = (blockIdx.x*256 + threadIdx.x) >> 6;
  int lane = threadIdx.x & 63;
  int qt = lane >> 4, l16 = lane & 15;
  int w = wv*4 + qt;
  if (w >= nNodes) return;
  int beg = rowptr[w], end = rowptr[w+1];
  float erw = er[w];
  float4 bv0 = *(const float4*)(bias + l16*8);
  float4 bv1 = *(const float4*)(bias + l16*8 + 4);
  float a[8];
  #pragma unroll
  for (int f = 0; f < 8; ++f) a[f] = 0.f;
  float wsum = 0.f;
  for (int i = beg; i < end; i += 8) {
    int sI[8]; float lv[8]; short8v q[8];
    #pragma unroll
    for (int u = 0; u < 8; ++u) {
      int idx = i + u; idx = (idx < end) ? idx : (end - 1);
      sI[u] = srcp[idx];
    }
    #pragma unroll
    for (int u = 0; u < 8; ++u) lv[u] = el[sI[u]];
    #pragma unroll
    for (int u = 0; u < 8; ++u) q[u] = *(const short8v*)(z + (size_t)sI[u]*H_ + l16*8);
    #pragma unroll
    for (int u = 0; u < 8; ++u) {
      float wt = (i + u < end) ? __expf(lrelu02(lv[u] + erw)) : 0.f;
      #pragma unroll
      for (int f = 0; f < 8; ++f)
        a[f] += wt*bf16_tof((unsigned short)q[u][f]);
      wsum += wt;
    }
  }
  float inv = (end > beg) ? fast_rcp(wsum) : 0.f;
  float o[8];
  o[0] = a[0]*inv + bv0.x; o[1] = a[1]*inv + bv0.y;
  o[2] = a[2]*inv + bv0.z; o[3] = a[3]*inv + bv0.w;
  o[4] = a[4]*inv + bv1.x; o[5] = a[5]*inv + bv1.y;
  o[6] = a[6]*inv + bv1.z; o[7] = a[7]*inv + bv1.w;
  short8v hv, lv8;
  #pragma unroll
  for (int f = 0; f < 8; ++f) {
    unsigned short h = bf16_rne(o[f]);
    hv[f] = (short)h;
    lv8[f] = (short)bf16_rne(o[f] - bf16_tof(h));
  }
  *(short8v*)(outHi + (size_t)w*H_ + l16*8) = hv;
  *(short8v*)(outLo + (size_t)w*H_ + l16*8) = lv8;
}

// ---------- MFMA split-bf16 GEMM: C/Cb[M,128] = (Ahi+Alo)@(Whi+Wlo), WT[col][k] ----------
__global__ __launch_bounds__(256) void k_mfma_gemm(
    const unsigned short* __restrict__ Ahi, const unsigned short* __restrict__ Alo,
    const unsigned short* __restrict__ WThi, const unsigned short* __restrict__ WTlo,
    float* __restrict__ C, unsigned short* __restrict__ Cb,
    const float* __restrict__ al, const float* __restrict__ ar,
    float* __restrict__ el, float* __restrict__ er) {
  __shared__ unsigned short lAhi[64*136];
  __shared__ unsigned short lAlo[64*136];
  __shared__ float redl[4][64];
  __shared__ float redr[4][64];
  int t = threadIdx.x;
  int row0 = blockIdx.x * 64;
  int wid = t >> 6, lane = t & 63;
  int g = lane >> 4, c = lane & 15;

  #pragma unroll
  for (int i = 0; i < 4; ++i) {
    int m = t + 256*i;
    int r = m >> 4;
    int kc = (m & 15) * 8;
    *(short8v*)(lAhi + r*136 + kc) = *(const short8v*)(Ahi + (size_t)(row0 + r)*H_ + kc);
    *(short8v*)(lAlo + r*136 + kc) = *(const short8v*)(Alo + (size_t)(row0 + r)*H_ + kc);
  }

  short8v bhi[2][4], blo[2][4];
  #pragma unroll
  for (int ct = 0; ct < 2; ++ct) {
    int col = wid*32 + ct*16 + c;
    #pragma unroll
    for (int kb = 0; kb < 4; ++kb) {
      size_t o = (size_t)col*H_ + kb*32 + g*8;
      bhi[ct][kb] = *(const short8v*)(WThi + o);
      blo[ct][kb] = *(const short8v*)(WTlo + o);
    }
  }

  floatx4 acc[4][2];
  #pragma unroll
  for (int rt = 0; rt < 4; ++rt)
    #pragma unroll
    for (int ct = 0; ct < 2; ++ct)
      acc[rt][ct] = (floatx4){0.f, 0.f, 0.f, 0.f};

  __syncthreads();

  #pragma unroll
  for (int kb = 0; kb < 4; ++kb) {
    short8v ahi[4], alo[4];
    #pragma unroll
    for (int rt = 0; rt < 4; ++rt) {
      int r = rt*16 + c;
      ahi[rt] = *(const short8v*)(lAhi + r*136 + kb*32 + g*8);
      alo[rt] = *(const short8v*)(lAlo + r*136 + kb*32 + g*8);
    }
    #pragma unroll
    for (int rt = 0; rt < 4; ++rt)
      #pragma unroll
      for (int ct = 0; ct < 2; ++ct) {
        acc[rt][ct] = __builtin_amdgcn_mfma_f32_16x16x32_bf16(ahi[rt], bhi[ct][kb], acc[rt][ct], 0, 0, 0);
        acc[rt][ct] = __builtin_amdgcn_mfma_f32_16x16x32_bf16(alo[rt], bhi[ct][kb], acc[rt][ct], 0, 0, 0);
        acc[rt][ct] = __builtin_amdgcn_mfma_f32_16x16x32_bf16(ahi[rt], blo[ct][kb], acc[rt][ct], 0, 0, 0);
      }
  }

  #pragma unroll
  for (int rt = 0; rt < 4; ++rt)
    #pragma unroll
    for (int i = 0; i < 4; ++i) {
      int row = row0 + rt*16 + g*4 + i;
      if (Cb) {
        unsigned short* cr = Cb + (size_t)row*H_ + wid*32;
        cr[c]      = bf16_rne(acc[rt][0][i]);
        cr[16 + c] = bf16_rne(acc[rt][1][i]);
      } else {
        float* cr = C + (size_t)row*H_ + wid*32;
        cr[c]      = acc[rt][0][i];
        cr[16 + c] = acc[rt][1][i];
      }
    }

  if (el) {
    float av0 = al[wid*32 + c], av1 = al[wid*32 + 16 + c];
    float rv0 = ar[wid*32 + c], rv1 = ar[wid*32 + 16 + c];
    #pragma unroll
    for (int rt = 0; rt < 4; ++rt)
      #pragma unroll
      for (int i = 0; i < 4; ++i) {
        float pl = acc[rt][0][i]*av0 + acc[rt][1][i]*av1;
        float pr = acc[rt][0][i]*rv0 + acc[rt][1][i]*rv1;
        pl += __shfl_xor(pl, 1, 64); pl += __shfl_xor(pl, 2, 64);
        pl += __shfl_xor(pl, 4, 64); pl += __shfl_xor(pl, 8, 64);
        pr += __shfl_xor(pr, 1, 64); pr += __shfl_xor(pr, 2, 64);
        pr += __shfl_xor(pr, 4, 64); pr += __shfl_xor(pr, 8, 64);
        if (c == 0) { redl[wid][rt*16 + g*4 + i] = pl; redr[wid][rt*16 + g*4 + i] = pr; }
      }
    __syncthreads();
    if (t < 64) {
      el[row0 + t] = redl[0][t] + redl[1][t] + redl[2][t] + redl[3][t];
      er[row0 + t] = redr[0][t] + redr[1][t] + redr[2][t] + redr[3][t];
    }
  }
}

// ---------- FUSED A1-MFMA + attention v2: LDS relay (no atomics) ----------
__global__ __launch_bounds__(256) void k_mfma_attn(
    const unsigned short* __restrict__ Ahi, const unsigned short* __restrict__ Alo,
    const unsigned short* __restrict__ WThi, const unsigned short* __restrict__ WTlo,
    const float* __restrict__ A2, const float* __restrict__ v_attn,
    const int* __restrict__ vnr_VNF, const int* __restrict__ net_VNF,
    float* __restrict__ pi) {
  __shared__ unsigned short lA[2][64*136];   // staging; reused as f32 A1 tile [64][132]
  __shared__ float a2s2[2][10][128];         // 2*A2 for the <=2 batches this block spans
  __shared__ float vv2s[128];                // 2*v
  int t = threadIdx.x;
  int row0 = blockIdx.x * 64;
  int wid = t >> 6, lane = t & 63;
  int g = lane >> 4, c = lane & 15;
  int b0 = row0 / NN_;
  int b1 = (row0 + 63) / NN_; if (b1 > B_-1) b1 = B_-1;

  unsigned short* lAhi = lA[0];
  unsigned short* lAlo = lA[1];
  #pragma unroll
  for (int i = 0; i < 4; ++i) {
    int m = t + 256*i;
    int r = m >> 4;
    int kc = (m & 15) * 8;
    *(short8v*)(lAhi + r*136 + kc) = *(const short8v*)(Ahi + (size_t)(row0 + r)*H_ + kc);
    *(short8v*)(lAlo + r*136 + kc) = *(const short8v*)(Alo + (size_t)(row0 + r)*H_ + kc);
  }
  // stage 2*A2 for both candidate batches (each slab is 10*128=1280 floats)
  for (int i = t; i < 2560; i += 256) {
    int w = (i >= 1280) ? 1 : 0;
    int rem = i - w*1280;
    int s = rem >> 7, k = rem & 127;
    int b = (w == 0) ? b0 : b1;
    a2s2[w][s][k] = 2.f*A2[((size_t)s*B_ + b)*H_ + k];
  }
  if (t < 128) vv2s[t] = 2.f*v_attn[t];

  short8v bhi[2][4], blo[2][4];
  #pragma unroll
  for (int ct = 0; ct < 2; ++ct) {
    int col = wid*32 + ct*16 + c;
    #pragma unroll
    for (int kb = 0; kb < 4; ++kb) {
      size_t o = (size_t)col*H_ + kb*32 + g*8;
      bhi[ct][kb] = *(const short8v*)(WThi + o);
      blo[ct][kb] = *(const short8v*)(WTlo + o);
    }
  }

  floatx4 acc[4][2];
  #pragma unroll
  for (int rt = 0; rt < 4; ++rt)
    #pragma unroll
    for (int ct = 0; ct < 2; ++ct)
      acc[rt][ct] = (floatx4){0.f, 0.f, 0.f, 0.f};

  __syncthreads();

  #pragma unroll
  for (int kb = 0; kb < 4; ++kb) {
    short8v ahi[4], alo[4];
    #pragma unroll
    for (int rt = 0; rt < 4; ++rt) {
      int r = rt*16 + c;
      ahi[rt] = *(const short8v*)(lAhi + r*136 + kb*32 + g*8);
      alo[rt] = *(const short8v*)(lAlo + r*136 + kb*32 + g*8);
    }
    #pragma unroll
    for (int rt = 0; rt < 4; ++rt)
      #pragma unroll
      for (int ct = 0; ct < 2; ++ct) {
        acc[rt][ct] = __builtin_amdgcn_mfma_f32_16x16x32_bf16(ahi[rt], bhi[ct][kb], acc[rt][ct], 0, 0, 0);
        acc[rt][ct] = __builtin_amdgcn_mfma_f32_16x16x32_bf16(alo[rt], bhi[ct][kb], acc[rt][ct], 0, 0, 0);
        acc[rt][ct] = __builtin_amdgcn_mfma_f32_16x16x32_bf16(ahi[rt], blo[ct][kb], acc[rt][ct], 0, 0, 0);
      }
  }

  __syncthreads();   // all waves done reading staging LDS

  // relay: write f32 A1 tile (stride 132 words; 2-way bank aliasing only)
  float* a1s = (float*)lA;
  #pragma unroll
  for (int rt = 0; rt < 4; ++rt)
    #pragma unroll
    for (int i = 0; i < 4; ++i) {
      int lrow = rt*16 + g*4 + i;
      a1s[lrow*132 + wid*32 + c]      = acc[rt][0][i];
      a1s[lrow*132 + wid*32 + 16 + c] = acc[rt][1][i];
    }
  __syncthreads();

  // attn3 epilogue: thread owns (row nl, quarter p)
  int nl = t >> 2, p = t & 3;
  int row = row0 + nl;
  int b = row / NN_, n = row - b*NN_;
  int w = (b != b0) ? 1 : 0;
  const float* arow = a1s + nl*132 + p*32;
  float4 a[8], w2[8];
  #pragma unroll
  for (int kk = 0; kk < 8; ++kk) {
    float4 av = *(const float4*)(arow + kk*4);
    a[kk] = make_float4(2.f*av.x, 2.f*av.y, 2.f*av.z, 2.f*av.w);
    w2[kk] = *(const float4*)(&vv2s[p*32 + kk*4]);
  }
  float vsum = 0.f;
  #pragma unroll
  for (int kk = 0; kk < 8; ++kk)
    vsum += (w2[kk].x + w2[kk].y) + (w2[kk].z + w2[kk].w);
  vsum *= 0.5f;
  float accs[10];
  #pragma unroll
  for (int s = 0; s < 10; ++s) {
    const float* a2r = &a2s2[w][s][p*32];
    float sum2 = 0.f;
    #pragma unroll
    for (int kk = 0; kk < 8; ++kk) {
      float4 cc = *(const float4*)(a2r + kk*4);
      sum2 = fmaf(w2[kk].x, fast_rcp(1.f + __expf(a[kk].x + cc.x)), sum2);
      sum2 = fmaf(w2[kk].y, fast_rcp(1.f + __expf(a[kk].y + cc.y)), sum2);
      sum2 = fmaf(w2[kk].z, fast_rcp(1.f + __expf(a[kk].z + cc.z)), sum2);
      sum2 = fmaf(w2[kk].w, fast_rcp(1.f + __expf(a[kk].w + cc.w)), sum2);
    }
    accs[s] = vsum - sum2;
  }
  #pragma unroll
  for (int s = 0; s < 10; ++s) {
    accs[s] += __shfl_xor(accs[s], 1, 64);
    accs[s] += __shfl_xor(accs[s], 2, 64);
  }
  if (p == 0) {
    #pragma unroll
    for (int s = 0; s < 10; ++s) {
      int vnf = vnr_VNF[b*NV_ + s];
      int m   = net_VNF[(size_t)row*T_ + vnf];
      pi[(size_t)b*(NV_*NN_) + (size_t)s*NN_ + n] = accs[s] + __logf((float)m);
    }
  }
}

// ---------- FUSED aggregate -> MFMA GEMM (vnr path only: 10 blocks, tiny) ----------
__global__ __launch_bounds__(256) void k_agg_mfma(
    const int* __restrict__ rowptr, const unsigned short* __restrict__ srcp,
    const float* __restrict__ el_in, const float* __restrict__ er_in,
    const unsigned short* __restrict__ z_in, const float* __restrict__ bias,
    const unsigned short* __restrict__ WThi, const unsigned short* __restrict__ WTlo,
    unsigned short* __restrict__ zb_out, float* __restrict__ Cf,
    const float* __restrict__ al, const float* __restrict__ ar,
    float* __restrict__ el_out, float* __restrict__ er_out) {
  __shared__ unsigned short lAhi[64*136];
  __shared__ unsigned short lAlo[64*136];
  __shared__ float redl[4][64];
  __shared__ float redr[4][64];
  int t = threadIdx.x;
  int row0 = blockIdx.x * 64;
  int wid = t >> 6, lane = t & 63;
  int g = lane >> 4, c = lane & 15;

  float b0 = bias[lane*2], b1 = bias[lane*2 + 1];

  for (int j = 0; j < 8; ++j) {
    int wA = row0 + wid*16 + 2*j;
    int wB = wA + 1;
    int begA = rowptr[wA], endA = rowptr[wA+1];
    int begB = rowptr[wB], endB = rowptr[wB+1];
    float erA = er_in[wA], erB = er_in[wB];
    float a0A = 0.f, a1A = 0.f, wsA = 0.f;
    float a0B = 0.f, a1B = 0.f, wsB = 0.f;
    int iA = begA, iB = begB;
    while (iA < endA || iB < endB) {
      int sA[8], sB[8];
      #pragma unroll
      for (int u = 0; u < 8; ++u) {
        sA[u] = (iA + u < endA) ? (int)srcp[iA + u] : 0;
        sB[u] = (iB + u < endB) ? (int)srcp[iB + u] : 0;
      }
      float lA[8], lB[8];
      #pragma unroll
      for (int u = 0; u < 8; ++u) { lA[u] = el_in[sA[u]]; lB[u] = el_in[sB[u]]; }
      ushort2 qA[8], qB[8];
      #pragma unroll
      for (int u = 0; u < 8; ++u) {
        qA[u] = *(const ushort2*)(z_in + (size_t)sA[u]*H_ + lane*2);
        qB[u] = *(const ushort2*)(z_in + (size_t)sB[u]*H_ + lane*2);
      }
      #pragma unroll
      for (int u = 0; u < 8; ++u) {
        float wtA = (iA + u < endA) ? __expf(lrelu02(lA[u] + erA)) : 0.f;
        float wtB = (iB + u < endB) ? __expf(lrelu02(lB[u] + erB)) : 0.f;
        a0A += wtA*bf16_tof(qA[u].x); a1A += wtA*bf16_tof(qA[u].y); wsA += wtA;
        a0B += wtB*bf16_tof(qB[u].x); a1B += wtB*bf16_tof(qB[u].y); wsB += wtB;
      }
      iA += 8; iB += 8;
    }
    float invA = (endA > begA) ? fast_rcp(wsA) : 0.f;
    float invB = (endB > begB) ? fast_rcp(wsB) : 0.f;
    float o0A = a0A*invA + b0, o1A = a1A*invA + b1;
    float o0B = a0B*invB + b0, o1B = a1B*invB + b1;
    int rA = wid*16 + 2*j;
    unsigned short hA0 = bf16_rne(o0A), hA1 = bf16_rne(o1A);
    unsigned short hB0 = bf16_rne(o0B), hB1 = bf16_rne(o1B);
    ushort2 hvA; hvA.x = hA0; hvA.y = hA1;
    ushort2 lvA; lvA.x = bf16_rne(o0A - bf16_tof(hA0)); lvA.y = bf16_rne(o1A - bf16_tof(hA1));
    ushort2 hvB; hvB.x = hB0; hvB.y = hB1;
    ushort2 lvB; lvB.x = bf16_rne(o0B - bf16_tof(hB0)); lvB.y = bf16_rne(o1B - bf16_tof(hB1));
    *(ushort2*)(lAhi + rA*136 + lane*2) = hvA;
    *(ushort2*)(lAlo + rA*136 + lane*2) = lvA;
    *(ushort2*)(lAhi + (rA+1)*136 + lane*2) = hvB;
    *(ushort2*)(lAlo + (rA+1)*136 + lane*2) = lvB;
  }

  short8v bhi[2][4], blo[2][4];
  #pragma unroll
  for (int ct = 0; ct < 2; ++ct) {
    int col = wid*32 + ct*16 + c;
    #pragma unroll
    for (int kb = 0; kb < 4; ++kb) {
      size_t o = (size_t)col*H_ + kb*32 + g*8;
      bhi[ct][kb] = *(const short8v*)(WThi + o);
      blo[ct][kb] = *(const short8v*)(WTlo + o);
    }
  }

  floatx4 acc[4][2];
  #pragma unroll
  for (int rt = 0; rt < 4; ++rt)
    #pragma unroll
    for (int ct = 0; ct < 2; ++ct)
      acc[rt][ct] = (floatx4){0.f, 0.f, 0.f, 0.f};

  __syncthreads();

  #pragma unroll
  for (int kb = 0; kb < 4; ++kb) {
    short8v ahi[4], alo[4];
    #pragma unroll
    for (int rt = 0; rt < 4; ++rt) {
      int r = rt*16 + c;
      ahi[rt] = *(const short8v*)(lAhi + r*136 + kb*32 + g*8);
      alo[rt] = *(const short8v*)(lAlo + r*136 + kb*32 + g*8);
    }
    #pragma unroll
    for (int rt = 0; rt < 4; ++rt)
      #pragma unroll
      for (int ct = 0; ct < 2; ++ct) {
        acc[rt][ct] = __builtin_amdgcn_mfma_f32_16x16x32_bf16(ahi[rt], bhi[ct][kb], acc[rt][ct], 0, 0, 0);
        acc[rt][ct] = __builtin_amdgcn_mfma_f32_16x16x32_bf16(alo[rt], bhi[ct][kb], acc[rt][ct], 0, 0, 0);
        acc[rt][ct] = __builtin_amdgcn_mfma_f32_16x16x32_bf16(ahi[rt], blo[ct][kb], acc[rt][ct], 0, 0, 0);
      }
  }

  #pragma unroll
  for (int rt = 0; rt < 4; ++rt)
    #pragma unroll
    for (int i = 0; i < 4; ++i) {
      int row = row0 + rt*16 + g*4 + i;
      if (zb_out) {
        unsigned short* cr = zb_out + (size_t)row*H_ + wid*32;
        cr[c]      = bf16_rne(acc[rt][0][i]);
        cr[16 + c] = bf16_rne(acc[rt][1][i]);
      } else {
        float* cr = Cf + (size_t)row*H_ + wid*32;
        cr[c]      = acc[rt][0][i];
        cr[16 + c] = acc[rt][1][i];
      }
    }

  if (el_out) {
    float av0 = al[wid*32 + c], av1 = al[wid*32 + 16 + c];
    float rv0 = ar[wid*32 + c], rv1 = ar[wid*32 + 16 + c];
    #pragma unroll
    for (int rt = 0; rt < 4; ++rt)
      #pragma unroll
      for (int i = 0; i < 4; ++i) {
        float pl = acc[rt][0][i]*av0 + acc[rt][1][i]*av1;
        float pr = acc[rt][0][i]*rv0 + acc[rt][1][i]*rv1;
        pl += __shfl_xor(pl, 1, 64); pl += __shfl_xor(pl, 2, 64);
        pl += __shfl_xor(pl, 4, 64); pl += __shfl_xor(pl, 8, 64);
        pr += __shfl_xor(pr, 1, 64); pr += __shfl_xor(pr, 2, 64);
        pr += __shfl_xor(pr, 4, 64); pr += __shfl_xor(pr, 8, 64);
        if (c == 0) { redl[wid][rt*16 + g*4 + i] = pl; redr[wid][rt*16 + g*4 + i] = pr; }
      }
    __syncthreads();
    if (t < 64) {
      el_out[row0 + t] = redl[0][t] + redl[1][t] + redl[2][t] + redl[3][t];
      er_out[row0 + t] = redr[0][t] + redr[1][t] + redr[2][t] + redr[3][t];
    }
  }
}

// ---------- plain aggregate: bf16 z in, f32 out (vnr layer 3) ----------
__global__ __launch_bounds__(256) void k_aggregate_f(int nNodes, const int* __restrict__ rowptr,
    const unsigned short* __restrict__ srcp, const float* __restrict__ el,
    const float* __restrict__ er, const unsigned short* __restrict__ z,
    const float* __restrict__ bias, float* __restrict__ out) {
  int w = (blockIdx.x*256 + threadIdx.x) >> 6;
  int lane = threadIdx.x & 63;
  if (w >= nNodes) return;
  int beg = rowptr[w], end = rowptr[w+1];
  float erw = er[w];
  float a0 = 0.f, a1 = 0.f, wsum = 0.f;
  for (int i = beg; i < end; ++i) {
    int sI = srcp[i];
    float wt = __expf(lrelu02(el[sI] + erw));
    ushort2 q = *(const ushort2*)(z + (size_t)sI*H_ + lane*2);
    a0 += wt*bf16_tof(q.x); a1 += wt*bf16_tof(q.y); wsum += wt;
  }
  float inv = (end > beg) ? fast_rcp(wsum) : 0.f;
  float2 o;
  o.x = a0*inv + bias[lane*2];
  o.y = a1*inv + bias[lane*2 + 1];
  *(float2*)(out + (size_t)w*H_ + lane*2) = o;
}

// ---------- generic f32 GEMM (layer-1 static, layer-1 vnr, GI) ----------
__global__ __launch_bounds__(256) void k_gemm(const float* A, int M, int K, int N,
                                              const float* W, const float* bias,
                                              float* C, unsigned short* Cb,
                                              const float* al, const float* ar,
                                              float* el, float* er) {
  __shared__ float Ws_[64*128];
  __shared__ float As_[16*128];
  __shared__ float redl[16][17];
  __shared__ float redr[16][17];
  int t = threadIdx.x;
  int j0 = blockIdx.y * 128;
  int row0 = blockIdx.x * 16;
  for (int l = t; l < 16*K; l += 256) {
    int r = l / K, k = l - r*K;
    int row = row0 + r;
    As_[r*K + k] = (row < M) ? A[(size_t)row*K + k] : 0.f;
  }
  int jg = t & 15, r = t >> 4;
  float acc[8];
  #pragma unroll
  for (int q = 0; q < 8; ++q) acc[q] = 0.f;
  for (int kc = 0; kc < K; kc += 64) {
    int kl = min(64, K - kc);
    __syncthreads();
    for (int l = t; l < (kl << 7); l += 256) {
      int k = l >> 7, j = l & 127;
      int jj = j0 + j;
      Ws_[l] = (jj < N) ? W[(size_t)(kc + k)*N + jj] : 0.f;
    }
    __syncthreads();
    for (int k = 0; k < kl; ++k) {
      float a = As_[r*K + kc + k];
      const float* wr = &Ws_[(k << 7) + jg*8];
      #pragma unroll
      for (int q = 0; q < 8; ++q) acc[q] += a * wr[q];
    }
  }
  int row = row0 + r;
  if (row < M) {
    if (Cb) {
      unsigned short* crow = Cb + (size_t)row*N + j0 + jg*8;
      #pragma unroll
      for (int q = 0; q < 8; ++q) {
        int j = j0 + jg*8 + q;
        if (j < N) crow[q] = bf16_rne(acc[q] + (bias ? bias[j] : 0.f));
      }
    } else {
      float* crow = C + (size_t)row*N + j0 + jg*8;
      #pragma unroll
      for (int q = 0; q < 8; ++q) {
        int j = j0 + jg*8 + q;
        if (j < N) crow[q] = acc[q] + (bias ? bias[j] : 0.f);
      }
    }
  }
  if (el) {
    float pl = 0.f, pr = 0.f;
    #pragma unroll
    for (int q = 0; q < 8; ++q) {
      int j = jg*8 + q;
      pl += acc[q]*al[j];
      pr += acc[q]*ar[j];
    }
    redl[r][jg] = pl; redr[r][jg] = pr;
    __syncthreads();
    if (t < 16) {
      float sl = 0.f, sr = 0.f;
      for (int q = 0; q < 16; ++q) { sl += redl[t][q]; sr += redr[t][q]; }
      int row2 = row0 + t;
      if (row2 < M) { el[row2] = sl; er[row2] = sr; }
    }
  }
}

// ---------- GRU decoder: weights register-resident, LDS-broadcast h ----------
__global__ __launch_bounds__(512) void k_decoder(const float* __restrict__ GI,
                                                 const float* __restrict__ W_hh,
                                                 const float* __restrict__ b_hh,
                                                 const float* __restrict__ W_attn,
                                                 const float* __restrict__ h0,
                                                 float* __restrict__ A2) {
  int b = blockIdx.x;
  __shared__ float h[128];
  __shared__ float gh[384];
  int t = threadIdx.x;
  const float4* wsrc = (t < 384)
      ? (const float4*)(W_hh + (size_t)t*128)
      : (const float4*)(W_attn + (size_t)(t-384)*256 + 128);
  float4 wreg[32];
  #pragma unroll
  for (int kk = 0; kk < 32; ++kk) wreg[kk] = wsrc[kk];
  float bh = (t < 384) ? b_hh[t] : 0.f;
  if (t < 128) h[t] = h0[t];
  __syncthreads();
  for (int s = 0; s < 10; ++s) {
    const float4* h4 = (const float4*)h;
    if (t < 384) {
      float a0 = 0.f, a1 = 0.f, a2 = 0.f, a3 = 0.f;
      #pragma unroll
      for (int kk = 0; kk < 32; kk += 4) {
        a0 += dot4(wreg[kk+0], h4[kk+0]);
        a1 += dot4(wreg[kk+1], h4[kk+1]);
        a2 += dot4(wreg[kk+2], h4[kk+2]);
        a3 += dot4(wreg[kk+3], h4[kk+3]);
      }
      gh[t] = (a0 + a1) + (a2 + a3) + bh;
    }
    __syncthreads();
    if (t < 128) {
      const float* gi = GI + (size_t)(b*NV_ + s)*384;
      float rr = fast_sigmoid(gi[t]       + gh[t]);
      float zz = fast_sigmoid(gi[128 + t] + gh[128 + t]);
      float nn = fast_tanh   (gi[256 + t] + rr*gh[256 + t]);
      h[t] = (1.f - zz)*nn + zz*h[t];
    }
    __syncthreads();
    if (t >= 384) {
      float a0 = 0.f, a1 = 0.f, a2 = 0.f, a3 = 0.f;
      #pragma unroll
      for (int kk = 0; kk < 32; kk += 4) {
        a0 += dot4(wreg[kk+0], h4[kk+0]);
        a1 += dot4(wreg[kk+1], h4[kk+1]);
        a2 += dot4(wreg[kk+2], h4[kk+2]);
        a3 += dot4(wreg[kk+3], h4[kk+3]);
      }
      A2[((size_t)s*B_ + b)*128 + (t - 384)] = (a0 + a1) + (a2 + a3);
    }
  }
}

// ---------- value head ----------
__global__ __launch_bounds__(128) void k_y2s(const unsigned short* hi, const unsigned short* lo,
                                             float* y2) {
  int b = blockIdx.x, slice = blockIdx.y, h = threadIdx.x;
  int n0 = slice*125, n1 = n0 + 125;
  float s = 0.f;
  for (int n = n0; n < n1; ++n) {
    size_t idx = ((size_t)b*NN_ + n)*H_ + h;
    s += bf16_tof(hi[idx]) + bf16_tof(lo[idx]);
  }
  atomicAdd(&y2[b*H_ + h], s);
}

__global__ __launch_bounds__(128) void k_value(const float* __restrict__ Hv,
                                               const float* __restrict__ nmask,
                                               const float* __restrict__ y2,
                                               const float* __restrict__ W_out,
                                               const float* __restrict__ b_out,
                                               float* __restrict__ val) {
  __shared__ float y1s[128];
  int b = blockIdx.x, t = threadIdx.x;
  float s = 0.f, d = 0.f;
  #pragma unroll
  for (int i = 0; i < NV_; ++i) {
    float m = nmask[b*NV_ + i];
    s += Hv[(size_t)(b*NV_ + i)*H_ + t]*m;
    d += m;
  }
  y1s[t] = s/d;
  __syncthreads();
  if (t < 64) {
    const float* w = W_out + (size_t)t*256;
    float acc = b_out[t];
    for (int h = 0; h < H_; ++h)
      acc += y1s[h]*w[h] + (y2[b*H_ + h]*(1.f/1000.f))*w[128 + h];
    val[b*O_ + t] = acc;
  }
}

extern "C" void kernel_launch(void* const* d_in, const int* in_sizes, int n_in,
                              void* d_out, int out_size, void* d_ws, size_t ws_size,
                              hipStream_t stream) {
  (void)in_sizes; (void)n_in; (void)out_size; (void)ws_size;
  const float* static_feat = (const float*)d_in[0];
  const float* vnr_feat    = (const float*)d_in[1];
  const float* nmask       = (const float*)d_in[2];
  const float* Ws1 = (const float*)d_in[3];  const float* als1 = (const float*)d_in[4];
  const float* ars1 = (const float*)d_in[5]; const float* bs1 = (const float*)d_in[6];
  const float* Ws2 = (const float*)d_in[7];  const float* als2 = (const float*)d_in[8];
  const float* ars2 = (const float*)d_in[9]; const float* bs2 = (const float*)d_in[10];
  const float* Ws3 = (const float*)d_in[11]; const float* als3 = (const float*)d_in[12];
  const float* ars3 = (const float*)d_in[13]; const float* bs3 = (const float*)d_in[14];
  const float* Wv1 = (const float*)d_in[15]; const float* alv1 = (const float*)d_in[16];
  const float* arv1 = (const float*)d_in[17]; const float* bv1 = (const float*)d_in[18];
  const float* Wv2 = (const float*)d_in[19]; const float* alv2 = (const float*)d_in[20];
  const float* arv2 = (const float*)d_in[21]; const float* bv2 = (const float*)d_in[22];
  const float* Wv3 = (const float*)d_in[23]; const float* alv3 = (const float*)d_in[24];
  const float* arv3 = (const float*)d_in[25]; const float* bv3 = (const float*)d_in[26];
  const float* W_attn = (const float*)d_in[27];
  const float* v_attn = (const float*)d_in[28];
  const float* W_ih = (const float*)d_in[29];
  const float* W_hh = (const float*)d_in[30];
  const float* b_ih = (const float*)d_in[31];
  const float* b_hh = (const float*)d_in[32];
  const float* h0   = (const float*)d_in[33];
  const float* W_out = (const float*)d_in[34];
  const float* b_out = (const float*)d_in[35];
  const int* src_s = (const int*)d_in[36];
  const int* dst_s = (const int*)d_in[37];
  const int* src_v = (const int*)d_in[38];
  const int* dst_v = (const int*)d_in[39];
  const int* vnr_VNF = (const int*)d_in[40];
  const int* net_VNF = (const int*)d_in[41];

  char* ws = (char*)d_ws;
  size_t off = 0;
  auto alloc = [&](size_t bytes) -> char* {
    off = (off + 255) & ~(size_t)255;
    char* p = ws + off;
    off += bytes;
    return p;
  };
  unsigned short* Zb0 = (unsigned short*)alloc((size_t)NS_*H_*2);   // bf16 z
  unsigned short* HsHi = (unsigned short*)alloc((size_t)NS_*H_*2);
  unsigned short* HsLo = (unsigned short*)alloc((size_t)NS_*H_*2);
  unsigned short* Zbv0 = (unsigned short*)alloc((size_t)NVT_*H_*2);
  unsigned short* Zbv1 = (unsigned short*)alloc((size_t)NVT_*H_*2);
  float* Hv   = (float*)alloc((size_t)NVT_*H_*4);
  float* el_s = (float*)alloc((size_t)NS_*4);
  float* er_s = (float*)alloc((size_t)NS_*4);
  float* elv_a = (float*)alloc((size_t)NVT_*4);
  float* erv_a = (float*)alloc((size_t)NVT_*4);
  float* elv_b = (float*)alloc((size_t)NVT_*4);
  float* erv_b = (float*)alloc((size_t)NVT_*4);
  size_t zcount = (size_t)NS_ + NS_ + NVT_ + NVT_ + B_*H_;
  char* zb = alloc(zcount*4);
  int*   counts_s = (int*)zb;
  int*   cursor_s = counts_s + NS_;
  int*   counts_v = cursor_s + NS_;
  int*   cursor_v = counts_v + NVT_;
  float* y2buf    = (float*)(cursor_v + NVT_);
  int* rowptr_s = (int*)alloc((size_t)(NS_+1)*4);
  int* rowptr_v = (int*)alloc((size_t)(NVT_+1)*4);
  int* bsum     = (int*)alloc((size_t)256*4);
  unsigned short* srcp_s = (unsigned short*)alloc((size_t)(EN_+8)*2);
  unsigned short* srcp_v = (unsigned short*)alloc((size_t)(EV_+8)*2);
  unsigned short* WS2hi = (unsigned short*)alloc((size_t)H_*H_*2);
  unsigned short* WS2lo = (unsigned short*)alloc((size_t)H_*H_*2);
  unsigned short* WS3hi = (unsigned short*)alloc((size_t)H_*H_*2);
  unsigned short* WS3lo = (unsigned short*)alloc((size_t)H_*H_*2);
  unsigned short* WAhi  = (unsigned short*)alloc((size_t)H_*H_*2);
  unsigned short* WAlo  = (unsigned short*)alloc((size_t)H_*H_*2);
  unsigned short* WV2hi = (unsigned short*)alloc((size_t)H_*H_*2);
  unsigned short* WV2lo = (unsigned short*)alloc((size_t)H_*H_*2);
  unsigned short* WV3hi = (unsigned short*)alloc((size_t)H_*H_*2);
  unsigned short* WV3lo = (unsigned short*)alloc((size_t)H_*H_*2);
  float* WTih   = (float*)alloc((size_t)H_*384*4);
  float* GI     = (float*)alloc((size_t)NVT_*384*4);
  float* A2     = (float*)alloc((size_t)NV_*B_*H_*4);

  float* pi  = (float*)d_out;
  float* val = pi + (size_t)B_*NV_*NN_;

  hipMemsetAsync(zb, 0, zcount*4, stream);

  k_prep<<<dim3(192, 6), 256, 0, stream>>>(W_ih, Ws2, Ws3, W_attn, Wv2, Wv3, WTih,
                                           WS2hi, WS2lo, WS3hi, WS3lo, WAhi, WAlo,
                                           WV2hi, WV2lo, WV3hi, WV3lo);

  // CSR build: XCD-ranged count + scatter
  int edgeChunks = (EN_ + EV_ + 255)/256;
  k_count_r<<<edgeChunks*8, 256, 0, stream>>>(dst_s, dst_v, counts_s, counts_v);
  k_scan_local<<<250, 256, 0, stream>>>(counts_s, NS_, rowptr_s, bsum);
  k_scan_small<<<2, 1024, 0, stream>>>(bsum, 250, counts_v, rowptr_v, NVT_);
  k_scan_add<<<250, 256, 0, stream>>>(rowptr_s, bsum, NS_, EN_);
  k_scatter_r<<<edgeChunks*8, 256, 0, stream>>>(src_s, dst_s, src_v, dst_v,
                                                rowptr_s, rowptr_v, cursor_s, cursor_v,
                                                srcp_s, srcp_v);

  int aggS = (NS_ + 15)/16;   // 4 nodes/wave, 4 waves/block -> 16 nodes/block

  // ---- static GAT stack ----
  k_gemm<<<dim3(NS_/16, 1), 256, 0, stream>>>(static_feat, NS_, FS_, H_, Ws1, nullptr,
                                              nullptr, Zb0, als1, ars1, el_s, er_s);
  k_aggregate_split<<<aggS, 256, 0, stream>>>(NS_, rowptr_s, srcp_s, el_s, er_s, Zb0, bs1, HsHi, HsLo);
  k_mfma_gemm<<<NS_/64, 256, 0, stream>>>(HsHi, HsLo, WS2hi, WS2lo, nullptr, Zb0, als2, ars2, el_s, er_s);
  k_aggregate_split<<<aggS, 256, 0, stream>>>(NS_, rowptr_s, srcp_s, el_s, er_s, Zb0, bs2, HsHi, HsLo);
  k_mfma_gemm<<<NS_/64, 256, 0, stream>>>(HsHi, HsLo, WS3hi, WS3lo, nullptr, Zb0, als3, ars3, el_s, er_s);
  k_aggregate_split<<<aggS, 256, 0, stream>>>(NS_, rowptr_s, srcp_s, el_s, er_s, Zb0, bs3, HsHi, HsLo);
  k_y2s<<<dim3(B_, 8), 128, 0, stream>>>(HsHi, HsLo, y2buf);

  // ---- vnr GAT stack (tiny: fused agg+GEMM, 10 blocks) ----
  k_gemm<<<dim3(NVT_/16, 1), 256, 0, stream>>>(vnr_feat, NVT_, FV_, H_, Wv1, nullptr,
                                               nullptr, Zbv0, alv1, arv1, elv_a, erv_a);
  k_agg_mfma<<<NVT_/64, 256, 0, stream>>>(rowptr_v, srcp_v, elv_a, erv_a, Zbv0, bv1,
                                          WV2hi, WV2lo, Zbv1, nullptr,
                                          alv2, arv2, elv_b, erv_b);
  k_agg_mfma<<<NVT_/64, 256, 0, stream>>>(rowptr_v, srcp_v, elv_b, erv_b, Zbv1, bv2,
                                          WV3hi, WV3lo, Zbv0, nullptr,
                                          alv3, arv3, elv_a, erv_a);
  k_aggregate_f<<<(NVT_ + 3)/4, 256, 0, stream>>>(NVT_, rowptr_v, srcp_v, elv_a, erv_a,
                                                  Zbv0, bv3, Hv);

  // ---- decoder ----
  k_gemm<<<dim3(NVT_/16, 3), 256, 0, stream>>>(Hv, NVT_, H_, 384, WTih, b_ih, GI, nullptr,
                                               nullptr, nullptr, nullptr, nullptr);
  k_decoder<<<B_, 512, 0, stream>>>(GI, W_hh, b_hh, W_attn, h0, A2);
  // fused A1-MFMA + attention (LDS relay; no Z round trip, no atomics)
  k_mfma_attn<<<NS_/64, 256, 0, stream>>>(HsHi, HsLo, WAhi, WAlo, A2, v_attn,
                                          vnr_VNF, net_VNF, pi);

  // ---- value head ----
  k_value<<<B_, 128, 0, stream>>>(Hv, nmask, y2buf, W_out, b_out, val);
}